// Round 1
// baseline (252.497 us; speedup 1.0000x reference)
//
#include <hip/hip_runtime.h>

#define DMODEL 256
#define NSEQ   2048
#define NB     4
#define NH     4
#define DHEAD  64

typedef __attribute__((ext_vector_type(8))) short short8;
typedef __attribute__((ext_vector_type(4))) float float4v;
typedef unsigned short u16;

static __device__ inline u16 f2bf(float f) {
    unsigned u = __builtin_bit_cast(unsigned, f);
    u += 0x7fffu + ((u >> 16) & 1u);   // round-to-nearest-even
    return (u16)(u >> 16);
}
static __device__ inline unsigned pack2bf(float a, float b) {
    return (unsigned)f2bf(a) | ((unsigned)f2bf(b) << 16);
}

// ---------------------------------------------------------------------------
// Input projections: out = W @ X + bias, X fp32 [b][256][2048].
// mode 0: Q -> q_ws[b][h][n][d] bf16, pre-scaled by 0.125*log2(e)
// mode 1: K -> k_ws[b][h][n][d] bf16
// mode 2: V -> vt_ws[b][h][d][n] bf16 (transposed)
// channel c = d*H + h  (reshape(b, DIM, H, N))
// ---------------------------------------------------------------------------
__global__ __launch_bounds__(256) void proj_qkv_kernel(
    const float* __restrict__ xq, const float* __restrict__ xk, const float* __restrict__ xv,
    const float* __restrict__ wqp, const float* __restrict__ wkp, const float* __restrict__ wvp,
    const float* __restrict__ bqp, const float* __restrict__ bkp, const float* __restrict__ bvp,
    u16* __restrict__ q_ws, u16* __restrict__ k_ws, u16* __restrict__ vt_ws)
{
    const int nt0 = blockIdx.x;            // 64-wide n tile
    const int ot  = blockIdx.y;            // 64-wide o tile
    const int bz  = blockIdx.z;            // b*3 + mode
    const int b = bz / 3, mode = bz % 3;

    const float* X  = (mode == 0) ? xq : (mode == 1) ? xk : xv;
    const float* W  = (mode == 0) ? wqp : (mode == 1) ? wkp : wvp;
    const float* BI = (mode == 0) ? bqp : (mode == 1) ? bkp : bvp;
    X += (size_t)b * DMODEL * NSEQ;

    const int tid = threadIdx.x;
    const int wave = tid >> 6, lane = tid & 63;
    const int g = lane >> 4, ql = lane & 15;

    __shared__ u16 xt[64][40];   // [n][c] (transposed), padded to 16B-aligned rows
    __shared__ u16 wt[64][40];   // [o][c]

    float4v acc[4];
    #pragma unroll
    for (int i = 0; i < 4; i++) acc[i] = (float4v){0.f, 0.f, 0.f, 0.f};

    const int obase = ot * 64, nbase = nt0 * 64;

    for (int c0 = 0; c0 < DMODEL; c0 += 32) {
        #pragma unroll
        for (int i = 0; i < 8; i++) {            // X chunk: 32c x 64n
            int e = tid + i * 256;
            int n = e & 63, c = e >> 6;
            xt[n][c] = f2bf(X[(size_t)(c0 + c) * NSEQ + nbase + n]);
        }
        #pragma unroll
        for (int i = 0; i < 8; i++) {            // W chunk: 64o x 32c
            int e = tid + i * 256;
            int o = e >> 5, c = e & 31;
            wt[o][c] = f2bf(W[(size_t)(obase + o) * DMODEL + c0 + c]);
        }
        __syncthreads();
        short8 afrag = *(const short8*)&wt[wave * 16 + ql][g * 8];
        #pragma unroll
        for (int nt = 0; nt < 4; nt++) {
            short8 bfrag = *(const short8*)&xt[nt * 16 + ql][g * 8];
            acc[nt] = __builtin_amdgcn_mfma_f32_16x16x32_bf16(afrag, bfrag, acc[nt], 0, 0, 0);
        }
        __syncthreads();
    }

    const int o0 = obase + wave * 16 + g * 4;
    #pragma unroll
    for (int nt = 0; nt < 4; nt++) {
        int n = nbase + nt * 16 + ql;
        #pragma unroll
        for (int r = 0; r < 4; r++) {
            int o = o0 + r;
            float v = acc[nt][r] + BI[o];
            int d = o >> 2, h = o & 3;
            if (mode == 0) {
                v *= 0.18033688011112042f;   // 0.125 * log2(e)
                q_ws[((size_t)(b * NH + h) * NSEQ + n) * DHEAD + d] = f2bf(v);
            } else if (mode == 1) {
                k_ws[((size_t)(b * NH + h) * NSEQ + n) * DHEAD + d] = f2bf(v);
            } else {
                vt_ws[((size_t)(b * NH + h) * DHEAD + d) * NSEQ + n] = f2bf(v);
            }
        }
    }
}

// ---------------------------------------------------------------------------
// Flash attention. 1 wave = 16 queries; block = 4 waves = 64 queries of one
// (b,h). S^T = K.Q^T via MFMA (D: col=lane&15=q, row=4g+r=m_local), online
// softmax in registers, P via per-wave LDS buffer, x^T = V^T.P^T via MFMA.
// ---------------------------------------------------------------------------
__global__ __launch_bounds__(256) void attn_kernel(
    const u16* __restrict__ q_ws, const u16* __restrict__ k_ws,
    const u16* __restrict__ vt_ws, u16* __restrict__ x_ws)
{
    const int qt = blockIdx.x;                 // 0..31
    const int h = blockIdx.y, b = blockIdx.z;
    const int tid = threadIdx.x, wave = tid >> 6, lane = tid & 63;
    const int g = lane >> 4, ql = lane & 15;
    const int bh = b * NH + h;
    const int qbase = qt * 64 + wave * 16;

    const u16* qp = q_ws + ((size_t)bh * NSEQ + qbase) * DHEAD;
    const u16* kp = k_ws + (size_t)bh * NSEQ * DHEAD;
    const u16* vp = vt_ws + (size_t)bh * DHEAD * NSEQ;

    __shared__ u16 p_lds[4][16][72];           // per-wave [q][m], rows 16B-aligned

    short8 qf[2];
    #pragma unroll
    for (int kc = 0; kc < 2; kc++)
        qf[kc] = *(const short8*)(qp + (size_t)ql * DHEAD + kc * 32 + g * 8);

    float4v acc[4];
    #pragma unroll
    for (int t = 0; t < 4; t++) acc[t] = (float4v){0.f, 0.f, 0.f, 0.f};
    float mrun = -INFINITY, lrun = 0.f;

    for (int mb = 0; mb < NSEQ; mb += 64) {
        // ---- scores: 4 tiles of S^T (16 m each), f32 accum
        float4v st[4];
        #pragma unroll
        for (int mt = 0; mt < 4; mt++) {
            st[mt] = (float4v){0.f, 0.f, 0.f, 0.f};
            #pragma unroll
            for (int kc = 0; kc < 2; kc++) {
                short8 kf = *(const short8*)(kp + (size_t)(mb + mt * 16 + ql) * DHEAD + kc * 32 + g * 8);
                st[mt] = __builtin_amdgcn_mfma_f32_16x16x32_bf16(kf, qf[kc], st[mt], 0, 0, 0);
            }
        }
        // ---- online softmax (scores already in log2 units)
        float tmax = -INFINITY;
        #pragma unroll
        for (int mt = 0; mt < 4; mt++)
            #pragma unroll
            for (int r = 0; r < 4; r++) tmax = fmaxf(tmax, st[mt][r]);
        tmax = fmaxf(tmax, __shfl_xor(tmax, 16, 64));
        tmax = fmaxf(tmax, __shfl_xor(tmax, 32, 64));
        float mnew = fmaxf(mrun, tmax);
        float alpha = exp2f(mrun - mnew);
        mrun = mnew;

        float p[16];
        float psum = 0.f;
        #pragma unroll
        for (int mt = 0; mt < 4; mt++)
            #pragma unroll
            for (int r = 0; r < 4; r++) {
                float e = exp2f(st[mt][r] - mnew);
                p[mt * 4 + r] = e;
                psum += e;
            }
        psum += __shfl_xor(psum, 16, 64);
        psum += __shfl_xor(psum, 32, 64);
        lrun = lrun * alpha + psum;

        #pragma unroll
        for (int t = 0; t < 4; t++)
            #pragma unroll
            for (int r = 0; r < 4; r++) acc[t][r] *= alpha;

        // ---- P -> LDS (bf16), re-fragment for PV
        #pragma unroll
        for (int mt = 0; mt < 4; mt++) {
            unsigned* dst = (unsigned*)&p_lds[wave][ql][mt * 16 + g * 4];
            dst[0] = pack2bf(p[mt * 4 + 0], p[mt * 4 + 1]);
            dst[1] = pack2bf(p[mt * 4 + 2], p[mt * 4 + 3]);
        }
        __syncthreads();

        // ---- PV: x^T[d][q] += V^T[d][m] * P^T[m][q]
        #pragma unroll
        for (int kc = 0; kc < 2; kc++) {
            short8 pf = *(const short8*)&p_lds[wave][ql][kc * 32 + g * 8];
            #pragma unroll
            for (int t = 0; t < 4; t++) {
                short8 vf = *(const short8*)(vp + (size_t)(t * 16 + ql) * NSEQ + mb + kc * 32 + g * 8);
                acc[t] = __builtin_amdgcn_mfma_f32_16x16x32_bf16(vf, pf, acc[t], 0, 0, 0);
            }
        }
    }

    float inv = 1.f / lrun;
    #pragma unroll
    for (int t = 0; t < 4; t++)
        #pragma unroll
        for (int r = 0; r < 4; r++) {
            int d = t * 16 + g * 4 + r;
            int c = d * NH + h;
            x_ws[((size_t)b * DMODEL + c) * NSEQ + qbase + ql] = f2bf(acc[t][r] * inv);
        }
}

// ---------------------------------------------------------------------------
// Output projection: out = Wm @ x + bm, x bf16 [b][256][2048], out fp32.
// ---------------------------------------------------------------------------
__global__ __launch_bounds__(256) void proj_out_kernel(
    const u16* __restrict__ xw, const float* __restrict__ wm,
    const float* __restrict__ bm, float* __restrict__ out)
{
    const int nt0 = blockIdx.x, ot = blockIdx.y, b = blockIdx.z;
    const u16* X = xw + (size_t)b * DMODEL * NSEQ;

    const int tid = threadIdx.x;
    const int wave = tid >> 6, lane = tid & 63;
    const int g = lane >> 4, ql = lane & 15;

    __shared__ u16 xt[64][40];
    __shared__ u16 wt[64][40];

    float4v acc[4];
    #pragma unroll
    for (int i = 0; i < 4; i++) acc[i] = (float4v){0.f, 0.f, 0.f, 0.f};

    const int obase = ot * 64, nbase = nt0 * 64;

    for (int c0 = 0; c0 < DMODEL; c0 += 32) {
        #pragma unroll
        for (int i = 0; i < 8; i++) {
            int e = tid + i * 256;
            int n = e & 63, c = e >> 6;
            xt[n][c] = X[(size_t)(c0 + c) * NSEQ + nbase + n];
        }
        #pragma unroll
        for (int i = 0; i < 8; i++) {
            int e = tid + i * 256;
            int o = e >> 5, c = e & 31;
            wt[o][c] = f2bf(wm[(size_t)(obase + o) * DMODEL + c0 + c]);
        }
        __syncthreads();
        short8 afrag = *(const short8*)&wt[wave * 16 + ql][g * 8];
        #pragma unroll
        for (int nt = 0; nt < 4; nt++) {
            short8 bfrag = *(const short8*)&xt[nt * 16 + ql][g * 8];
            acc[nt] = __builtin_amdgcn_mfma_f32_16x16x32_bf16(afrag, bfrag, acc[nt], 0, 0, 0);
        }
        __syncthreads();
    }

    const int o0 = obase + wave * 16 + g * 4;
    #pragma unroll
    for (int nt = 0; nt < 4; nt++) {
        int n = nbase + nt * 16 + ql;
        #pragma unroll
        for (int r = 0; r < 4; r++) {
            int o = o0 + r;
            out[((size_t)b * DMODEL + o) * NSEQ + n] = acc[nt][r] + bm[o];
        }
    }
}

// ---------------------------------------------------------------------------
extern "C" void kernel_launch(void* const* d_in, const int* in_sizes, int n_in,
                              void* d_out, int out_size, void* d_ws, size_t ws_size,
                              hipStream_t stream)
{
    const float* query = (const float*)d_in[0];
    const float* key   = (const float*)d_in[1];
    const float* value = (const float*)d_in[2];
    const float* wq = (const float*)d_in[3];
    const float* bq = (const float*)d_in[4];
    const float* wk = (const float*)d_in[5];
    const float* bk = (const float*)d_in[6];
    const float* wv = (const float*)d_in[7];
    const float* bv = (const float*)d_in[8];
    const float* wm = (const float*)d_in[9];
    const float* bm = (const float*)d_in[10];
    float* out = (float*)d_out;

    char* ws = (char*)d_ws;
    const size_t SEG = (size_t)NB * NH * NSEQ * DHEAD * sizeof(u16);  // 4 MiB
    u16* q_ws  = (u16*)(ws);
    u16* k_ws  = (u16*)(ws + SEG);
    u16* vt_ws = (u16*)(ws + 2 * SEG);
    u16* x_ws  = (u16*)(ws + 3 * SEG);

    proj_qkv_kernel<<<dim3(32, 4, 12), 256, 0, stream>>>(
        query, key, value, wq, wk, wv, bq, bk, bv, q_ws, k_ws, vt_ws);
    attn_kernel<<<dim3(32, NH, NB), 256, 0, stream>>>(q_ws, k_ws, vt_ws, x_ws);
    proj_out_kernel<<<dim3(32, 4, NB), 256, 0, stream>>>(x_ws, wm, bm, out);
}

// Round 2
// 205.953 us; speedup vs baseline: 1.2260x; 1.2260x over previous
//
#include <hip/hip_runtime.h>

#define DMODEL 256
#define NSEQ   2048
#define NB     4
#define NH     4
#define DHEAD  64

typedef __attribute__((ext_vector_type(8))) short short8;
typedef __attribute__((ext_vector_type(4))) float float4v;
typedef __attribute__((ext_vector_type(2))) unsigned int uint2v;
typedef unsigned short u16;

static __device__ inline u16 f2bf(float f) {
    unsigned u = __builtin_bit_cast(unsigned, f);
    u += 0x7fffu + ((u >> 16) & 1u);   // round-to-nearest-even
    return (u16)(u >> 16);
}
static __device__ inline unsigned pack2bf(float a, float b) {
    return (unsigned)f2bf(a) | ((unsigned)f2bf(b) << 16);
}

// ---------------------------------------------------------------------------
// Input projections: out = W @ X + bias, X fp32 [b][256][2048].
// W rows are staged PERMUTED (m -> ((m&3)<<2)|(m>>2) within each 16-row tile)
// so epilogue lane (g,ql) rows r=0..3 map to o = base + 4r + g:
//   h = o&3 = g (fixed), d = o>>2 = d0 + r (consecutive) -> 8B packed stores.
// mode 0: Q -> q_ws[b][h][n][d] bf16, pre-scaled by 0.125*log2(e)
// mode 1: K -> k_ws[b][h][n][d] bf16
// mode 2: V -> vt_ws[b][h][d][n] bf16 (transposed)
// ---------------------------------------------------------------------------
__global__ __launch_bounds__(256) void proj_qkv_kernel(
    const float* __restrict__ xq, const float* __restrict__ xk, const float* __restrict__ xv,
    const float* __restrict__ wqp, const float* __restrict__ wkp, const float* __restrict__ wvp,
    const float* __restrict__ bqp, const float* __restrict__ bkp, const float* __restrict__ bvp,
    u16* __restrict__ q_ws, u16* __restrict__ k_ws, u16* __restrict__ vt_ws)
{
    const int nt0 = blockIdx.x;            // 64-wide n tile
    const int ot  = blockIdx.y;            // 64-wide o tile
    const int bz  = blockIdx.z;            // b*3 + mode
    const int b = bz / 3, mode = bz % 3;

    const float* X  = (mode == 0) ? xq : (mode == 1) ? xk : xv;
    const float* W  = (mode == 0) ? wqp : (mode == 1) ? wkp : wvp;
    const float* BI = (mode == 0) ? bqp : (mode == 1) ? bkp : bvp;
    X += (size_t)b * DMODEL * NSEQ;

    const int tid = threadIdx.x;
    const int wave = tid >> 6, lane = tid & 63;
    const int g = lane >> 4, ql = lane & 15;

    __shared__ u16 xt[64][72];   // [n][c], rows 144B (16B multiple)
    __shared__ u16 wt[64][72];   // [o_perm][c]

    float4v acc[4];
    #pragma unroll
    for (int i = 0; i < 4; i++) acc[i] = (float4v){0.f, 0.f, 0.f, 0.f};

    const int obase = ot * 64, nbase = nt0 * 64;

    for (int c0 = 0; c0 < DMODEL; c0 += 64) {
        #pragma unroll
        for (int i = 0; i < 4; i++) {            // X chunk: 64c x 64n, float4 along n
            int e = tid + i * 256;
            int c = e >> 4, n4 = (e & 15) * 4;
            float4v xv4 = *(const float4v*)&X[(size_t)(c0 + c) * NSEQ + nbase + n4];
            xt[n4 + 0][c] = f2bf(xv4[0]);
            xt[n4 + 1][c] = f2bf(xv4[1]);
            xt[n4 + 2][c] = f2bf(xv4[2]);
            xt[n4 + 3][c] = f2bf(xv4[3]);
        }
        #pragma unroll
        for (int i = 0; i < 4; i++) {            // W chunk: 64o x 64c, float4 along c
            int e = tid + i * 256;
            int orow = e >> 4, c4 = (e & 15) * 4;
            int og = (orow & 48) | ((orow & 3) << 2) | ((orow >> 2) & 3);  // perm
            float4v wv4 = *(const float4v*)&W[(size_t)(obase + og) * DMODEL + c0 + c4];
            unsigned* dst = (unsigned*)&wt[orow][c4];
            dst[0] = pack2bf(wv4[0], wv4[1]);
            dst[1] = pack2bf(wv4[2], wv4[3]);
        }
        __syncthreads();
        #pragma unroll
        for (int kc = 0; kc < 2; kc++) {
            short8 afrag = *(const short8*)&wt[wave * 16 + ql][kc * 32 + g * 8];
            #pragma unroll
            for (int nt = 0; nt < 4; nt++) {
                short8 bfrag = *(const short8*)&xt[nt * 16 + ql][kc * 32 + g * 8];
                acc[nt] = __builtin_amdgcn_mfma_f32_16x16x32_bf16(afrag, bfrag, acc[nt], 0, 0, 0);
            }
        }
        __syncthreads();
    }

    // epilogue: lane rows r=0..3 -> o = obase + wave*16 + 4r + g
    const int h = g;
    const int d0 = (obase + wave * 16) >> 2;
    float bias[4];
    #pragma unroll
    for (int r = 0; r < 4; r++) bias[r] = BI[obase + wave * 16 + 4 * r + g];

    #pragma unroll
    for (int nt = 0; nt < 4; nt++) {
        int n = nbase + nt * 16 + ql;
        float v[4];
        #pragma unroll
        for (int r = 0; r < 4; r++) v[r] = acc[nt][r] + bias[r];
        if (mode == 0) {
            #pragma unroll
            for (int r = 0; r < 4; r++) v[r] *= 0.18033688011112042f;  // 0.125*log2(e)
            uint2v pk = {pack2bf(v[0], v[1]), pack2bf(v[2], v[3])};
            *(uint2v*)&q_ws[((size_t)(b * NH + h) * NSEQ + n) * DHEAD + d0] = pk;
        } else if (mode == 1) {
            uint2v pk = {pack2bf(v[0], v[1]), pack2bf(v[2], v[3])};
            *(uint2v*)&k_ws[((size_t)(b * NH + h) * NSEQ + n) * DHEAD + d0] = pk;
        } else {
            #pragma unroll
            for (int r = 0; r < 4; r++)
                vt_ws[((size_t)(b * NH + h) * DHEAD + d0 + r) * NSEQ + n] = f2bf(v[r]);
        }
    }
}

// ---------------------------------------------------------------------------
// Flash attention, 1 wave per block, 32 queries per wave (2 q-frags sharing
// every K/V fragment load). No barriers (p_lds is wave-private). Defer-max
// online softmax (THR=8 in log2 units; P bounded by 2^8, bf16-safe).
// ---------------------------------------------------------------------------
__global__ __launch_bounds__(64) void attn_kernel(
    const u16* __restrict__ q_ws, const u16* __restrict__ k_ws,
    const u16* __restrict__ vt_ws, u16* __restrict__ x_ws)
{
    const int qt0 = blockIdx.x;                // 0..63 (32-query tiles)
    const int h = blockIdx.y, b = blockIdx.z;
    const int lane = threadIdx.x;
    const int g = lane >> 4, ql = lane & 15;
    const int bh = b * NH + h;
    const int qbase = qt0 * 32;

    const u16* qp = q_ws + ((size_t)bh * NSEQ + qbase) * DHEAD;
    const u16* kp = k_ws + (size_t)bh * NSEQ * DHEAD;
    const u16* vp = vt_ws + (size_t)bh * DHEAD * NSEQ;

    __shared__ u16 p_lds[2][16][72];           // [qt][q][m], rows 144B

    short8 qf[2][2];
    #pragma unroll
    for (int qt = 0; qt < 2; qt++)
        #pragma unroll
        for (int kc = 0; kc < 2; kc++)
            qf[qt][kc] = *(const short8*)(qp + (size_t)(qt * 16 + ql) * DHEAD + kc * 32 + g * 8);

    float4v acc[2][4];
    #pragma unroll
    for (int qt = 0; qt < 2; qt++)
        #pragma unroll
        for (int t = 0; t < 4; t++) acc[qt][t] = (float4v){0.f, 0.f, 0.f, 0.f};
    float m0 = -INFINITY, m1 = -INFINITY, l0 = 0.f, l1 = 0.f;

    for (int mb = 0; mb < NSEQ; mb += 64) {
        // ---- S^T = K.Q^T, both q-frags share each K fragment
        float4v st[2][4];
        #pragma unroll
        for (int qt = 0; qt < 2; qt++)
            #pragma unroll
            for (int mt = 0; mt < 4; mt++) st[qt][mt] = (float4v){0.f, 0.f, 0.f, 0.f};
        #pragma unroll
        for (int mt = 0; mt < 4; mt++) {
            #pragma unroll
            for (int kc = 0; kc < 2; kc++) {
                short8 kf = *(const short8*)(kp + (size_t)(mb + mt * 16 + ql) * DHEAD + kc * 32 + g * 8);
                st[0][mt] = __builtin_amdgcn_mfma_f32_16x16x32_bf16(kf, qf[0][kc], st[0][mt], 0, 0, 0);
                st[1][mt] = __builtin_amdgcn_mfma_f32_16x16x32_bf16(kf, qf[1][kc], st[1][mt], 0, 0, 0);
            }
        }

        // ---- tile max (scores are in log2 units)
        float tmax0 = -INFINITY, tmax1 = -INFINITY;
        #pragma unroll
        for (int mt = 0; mt < 4; mt++)
            #pragma unroll
            for (int r = 0; r < 4; r++) {
                tmax0 = fmaxf(tmax0, st[0][mt][r]);
                tmax1 = fmaxf(tmax1, st[1][mt][r]);
            }
        tmax0 = fmaxf(tmax0, __shfl_xor(tmax0, 16, 64));
        tmax0 = fmaxf(tmax0, __shfl_xor(tmax0, 32, 64));
        tmax1 = fmaxf(tmax1, __shfl_xor(tmax1, 16, 64));
        tmax1 = fmaxf(tmax1, __shfl_xor(tmax1, 32, 64));

        // ---- defer-max: rescale only when a tile max jumps by >8 (2^8 headroom)
        bool need = (tmax0 > m0 + 8.f) || (tmax1 > m1 + 8.f);
        if (__any(need)) {
            float mn0 = fmaxf(m0, tmax0), mn1 = fmaxf(m1, tmax1);
            float a0 = __builtin_amdgcn_exp2f(m0 - mn0);
            float a1 = __builtin_amdgcn_exp2f(m1 - mn1);
            #pragma unroll
            for (int t = 0; t < 4; t++)
                #pragma unroll
                for (int r = 0; r < 4; r++) {
                    acc[0][t][r] *= a0;
                    acc[1][t][r] *= a1;
                }
            l0 *= a0; l1 *= a1;
            m0 = mn0; m1 = mn1;
        }

        // ---- P = exp2(S - m), row-sums, P -> wave-private LDS (bf16)
        float ps0 = 0.f, ps1 = 0.f;
        #pragma unroll
        for (int mt = 0; mt < 4; mt++) {
            float p0[4], p1[4];
            #pragma unroll
            for (int r = 0; r < 4; r++) {
                p0[r] = __builtin_amdgcn_exp2f(st[0][mt][r] - m0);
                p1[r] = __builtin_amdgcn_exp2f(st[1][mt][r] - m1);
                ps0 += p0[r];
                ps1 += p1[r];
            }
            unsigned* d0p = (unsigned*)&p_lds[0][ql][mt * 16 + g * 4];
            d0p[0] = pack2bf(p0[0], p0[1]);
            d0p[1] = pack2bf(p0[2], p0[3]);
            unsigned* d1p = (unsigned*)&p_lds[1][ql][mt * 16 + g * 4];
            d1p[0] = pack2bf(p1[0], p1[1]);
            d1p[1] = pack2bf(p1[2], p1[3]);
        }
        ps0 += __shfl_xor(ps0, 16, 64);
        ps0 += __shfl_xor(ps0, 32, 64);
        ps1 += __shfl_xor(ps1, 16, 64);
        ps1 += __shfl_xor(ps1, 32, 64);
        l0 += ps0; l1 += ps1;

        // ---- PV: x^T[d][q] += V^T[d][m] * P^T[m][q], V shared across q-frags
        #pragma unroll
        for (int kc = 0; kc < 2; kc++) {
            short8 pf0 = *(const short8*)&p_lds[0][ql][kc * 32 + g * 8];
            short8 pf1 = *(const short8*)&p_lds[1][ql][kc * 32 + g * 8];
            #pragma unroll
            for (int t = 0; t < 4; t++) {
                short8 vf = *(const short8*)(vp + (size_t)(t * 16 + ql) * NSEQ + mb + kc * 32 + g * 8);
                acc[0][t] = __builtin_amdgcn_mfma_f32_16x16x32_bf16(vf, pf0, acc[0][t], 0, 0, 0);
                acc[1][t] = __builtin_amdgcn_mfma_f32_16x16x32_bf16(vf, pf1, acc[1][t], 0, 0, 0);
            }
        }
    }

    float inv0 = 1.f / l0, inv1 = 1.f / l1;
    #pragma unroll
    for (int qt = 0; qt < 2; qt++) {
        float inv = qt ? inv1 : inv0;
        #pragma unroll
        for (int t = 0; t < 4; t++)
            #pragma unroll
            for (int r = 0; r < 4; r++) {
                int d = t * 16 + g * 4 + r;
                int c = d * NH + h;
                x_ws[((size_t)b * DMODEL + c) * NSEQ + qbase + qt * 16 + ql] = f2bf(acc[qt][t][r] * inv);
            }
    }
}

// ---------------------------------------------------------------------------
// Output projection: out = Wm @ x + bm, x bf16 [b][256][2048], out fp32.
// ---------------------------------------------------------------------------
__global__ __launch_bounds__(256) void proj_out_kernel(
    const u16* __restrict__ xw, const float* __restrict__ wm,
    const float* __restrict__ bm, float* __restrict__ out)
{
    const int nt0 = blockIdx.x, ot = blockIdx.y, b = blockIdx.z;
    const u16* X = xw + (size_t)b * DMODEL * NSEQ;

    const int tid = threadIdx.x;
    const int wave = tid >> 6, lane = tid & 63;
    const int g = lane >> 4, ql = lane & 15;

    __shared__ u16 xt[64][72];
    __shared__ u16 wt[64][72];

    float4v acc[4];
    #pragma unroll
    for (int i = 0; i < 4; i++) acc[i] = (float4v){0.f, 0.f, 0.f, 0.f};

    const int obase = ot * 64, nbase = nt0 * 64;

    for (int c0 = 0; c0 < DMODEL; c0 += 64) {
        #pragma unroll
        for (int i = 0; i < 2; i++) {            // X chunk: 64c x 64n bf16, 16B loads
            int e = tid + i * 256;
            int c = e >> 3, n8 = (e & 7) * 8;
            short8 xv8 = *(const short8*)&X[(size_t)(c0 + c) * NSEQ + nbase + n8];
            #pragma unroll
            for (int j = 0; j < 8; j++) xt[n8 + j][c] = (u16)xv8[j];
        }
        #pragma unroll
        for (int i = 0; i < 4; i++) {            // W chunk: 64o x 64c fp32, float4
            int e = tid + i * 256;
            int orow = e >> 4, c4 = (e & 15) * 4;
            float4v wv4 = *(const float4v*)&wm[(size_t)(obase + orow) * DMODEL + c0 + c4];
            unsigned* dst = (unsigned*)&wt[orow][c4];
            dst[0] = pack2bf(wv4[0], wv4[1]);
            dst[1] = pack2bf(wv4[2], wv4[3]);
        }
        __syncthreads();
        #pragma unroll
        for (int kc = 0; kc < 2; kc++) {
            short8 afrag = *(const short8*)&wt[wave * 16 + ql][kc * 32 + g * 8];
            #pragma unroll
            for (int nt = 0; nt < 4; nt++) {
                short8 bfrag = *(const short8*)&xt[nt * 16 + ql][kc * 32 + g * 8];
                acc[nt] = __builtin_amdgcn_mfma_f32_16x16x32_bf16(afrag, bfrag, acc[nt], 0, 0, 0);
            }
        }
        __syncthreads();
    }

    const int o0 = obase + wave * 16 + g * 4;
    #pragma unroll
    for (int nt = 0; nt < 4; nt++) {
        int n = nbase + nt * 16 + ql;
        #pragma unroll
        for (int r = 0; r < 4; r++) {
            int o = o0 + r;
            out[((size_t)b * DMODEL + o) * NSEQ + n] = acc[nt][r] + bm[o];
        }
    }
}

// ---------------------------------------------------------------------------
extern "C" void kernel_launch(void* const* d_in, const int* in_sizes, int n_in,
                              void* d_out, int out_size, void* d_ws, size_t ws_size,
                              hipStream_t stream)
{
    const float* query = (const float*)d_in[0];
    const float* key   = (const float*)d_in[1];
    const float* value = (const float*)d_in[2];
    const float* wq = (const float*)d_in[3];
    const float* bq = (const float*)d_in[4];
    const float* wk = (const float*)d_in[5];
    const float* bk = (const float*)d_in[6];
    const float* wv = (const float*)d_in[7];
    const float* bv = (const float*)d_in[8];
    const float* wm = (const float*)d_in[9];
    const float* bm = (const float*)d_in[10];
    float* out = (float*)d_out;

    char* ws = (char*)d_ws;
    const size_t SEG = (size_t)NB * NH * NSEQ * DHEAD * sizeof(u16);  // 4 MiB
    u16* q_ws  = (u16*)(ws);
    u16* k_ws  = (u16*)(ws + SEG);
    u16* vt_ws = (u16*)(ws + 2 * SEG);
    u16* x_ws  = (u16*)(ws + 3 * SEG);

    proj_qkv_kernel<<<dim3(32, 4, 12), 256, 0, stream>>>(
        query, key, value, wq, wk, wv, bq, bk, bv, q_ws, k_ws, vt_ws);
    attn_kernel<<<dim3(64, NH, NB), 64, 0, stream>>>(q_ws, k_ws, vt_ws, x_ws);
    proj_out_kernel<<<dim3(32, 4, NB), 256, 0, stream>>>(x_ws, wm, bm, out);
}

// Round 3
// 171.103 us; speedup vs baseline: 1.4757x; 1.2037x over previous
//
#include <hip/hip_runtime.h>

#define DMODEL 256
#define NSEQ   2048
#define NB     4
#define NH     4
#define DHEAD  64

typedef __attribute__((ext_vector_type(8))) short short8;
typedef __attribute__((ext_vector_type(4))) float float4v;
typedef __attribute__((ext_vector_type(2))) unsigned int uint2v;
typedef unsigned short u16;

static __device__ inline u16 f2bf(float f) {
    unsigned u = __builtin_bit_cast(unsigned, f);
    u += 0x7fffu + ((u >> 16) & 1u);   // round-to-nearest-even
    return (u16)(u >> 16);
}
static __device__ inline unsigned pack2bf(float a, float b) {
    return (unsigned)f2bf(a) | ((unsigned)f2bf(b) << 16);
}

// ---------------------------------------------------------------------------
// Input projections (unchanged from round 2): out = W @ X + bias.
// ---------------------------------------------------------------------------
__global__ __launch_bounds__(256) void proj_qkv_kernel(
    const float* __restrict__ xq, const float* __restrict__ xk, const float* __restrict__ xv,
    const float* __restrict__ wqp, const float* __restrict__ wkp, const float* __restrict__ wvp,
    const float* __restrict__ bqp, const float* __restrict__ bkp, const float* __restrict__ bvp,
    u16* __restrict__ q_ws, u16* __restrict__ k_ws, u16* __restrict__ vt_ws)
{
    const int nt0 = blockIdx.x;            // 64-wide n tile
    const int ot  = blockIdx.y;            // 64-wide o tile
    const int bz  = blockIdx.z;            // b*3 + mode
    const int b = bz / 3, mode = bz % 3;

    const float* X  = (mode == 0) ? xq : (mode == 1) ? xk : xv;
    const float* W  = (mode == 0) ? wqp : (mode == 1) ? wkp : wvp;
    const float* BI = (mode == 0) ? bqp : (mode == 1) ? bkp : bvp;
    X += (size_t)b * DMODEL * NSEQ;

    const int tid = threadIdx.x;
    const int wave = tid >> 6, lane = tid & 63;
    const int g = lane >> 4, ql = lane & 15;

    __shared__ u16 xt[64][72];   // [n][c]
    __shared__ u16 wt[64][72];   // [o_perm][c]

    float4v acc[4];
    #pragma unroll
    for (int i = 0; i < 4; i++) acc[i] = (float4v){0.f, 0.f, 0.f, 0.f};

    const int obase = ot * 64, nbase = nt0 * 64;

    for (int c0 = 0; c0 < DMODEL; c0 += 64) {
        #pragma unroll
        for (int i = 0; i < 4; i++) {            // X chunk: 64c x 64n, float4 along n
            int e = tid + i * 256;
            int c = e >> 4, n4 = (e & 15) * 4;
            float4v xv4 = *(const float4v*)&X[(size_t)(c0 + c) * NSEQ + nbase + n4];
            xt[n4 + 0][c] = f2bf(xv4[0]);
            xt[n4 + 1][c] = f2bf(xv4[1]);
            xt[n4 + 2][c] = f2bf(xv4[2]);
            xt[n4 + 3][c] = f2bf(xv4[3]);
        }
        #pragma unroll
        for (int i = 0; i < 4; i++) {            // W chunk: 64o x 64c, float4 along c
            int e = tid + i * 256;
            int orow = e >> 4, c4 = (e & 15) * 4;
            int og = (orow & 48) | ((orow & 3) << 2) | ((orow >> 2) & 3);  // perm
            float4v wv4 = *(const float4v*)&W[(size_t)(obase + og) * DMODEL + c0 + c4];
            unsigned* dst = (unsigned*)&wt[orow][c4];
            dst[0] = pack2bf(wv4[0], wv4[1]);
            dst[1] = pack2bf(wv4[2], wv4[3]);
        }
        __syncthreads();
        #pragma unroll
        for (int kc = 0; kc < 2; kc++) {
            short8 afrag = *(const short8*)&wt[wave * 16 + ql][kc * 32 + g * 8];
            #pragma unroll
            for (int nt = 0; nt < 4; nt++) {
                short8 bfrag = *(const short8*)&xt[nt * 16 + ql][kc * 32 + g * 8];
                acc[nt] = __builtin_amdgcn_mfma_f32_16x16x32_bf16(afrag, bfrag, acc[nt], 0, 0, 0);
            }
        }
        __syncthreads();
    }

    const int h = g;
    const int d0 = (obase + wave * 16) >> 2;
    float bias[4];
    #pragma unroll
    for (int r = 0; r < 4; r++) bias[r] = BI[obase + wave * 16 + 4 * r + g];

    #pragma unroll
    for (int nt = 0; nt < 4; nt++) {
        int n = nbase + nt * 16 + ql;
        float v[4];
        #pragma unroll
        for (int r = 0; r < 4; r++) v[r] = acc[nt][r] + bias[r];
        if (mode == 0) {
            #pragma unroll
            for (int r = 0; r < 4; r++) v[r] *= 0.18033688011112042f;  // 0.125*log2(e)
            uint2v pk = {pack2bf(v[0], v[1]), pack2bf(v[2], v[3])};
            *(uint2v*)&q_ws[((size_t)(b * NH + h) * NSEQ + n) * DHEAD + d0] = pk;
        } else if (mode == 1) {
            uint2v pk = {pack2bf(v[0], v[1]), pack2bf(v[2], v[3])};
            *(uint2v*)&k_ws[((size_t)(b * NH + h) * NSEQ + n) * DHEAD + d0] = pk;
        } else {
            #pragma unroll
            for (int r = 0; r < 4; r++)
                vt_ws[((size_t)(b * NH + h) * DHEAD + d0 + r) * NSEQ + n] = f2bf(v[r]);
        }
    }
}

// ---------------------------------------------------------------------------
// Flash attention v3: 4 waves/block, 32 q per wave (128 q/block), 256 blocks.
// XCD-swizzled block ids (2 heads per XCD -> K/V L2-resident).
// K/V tiles (64 keys) double-buffered in LDS via global_load_lds (16B, linear
// dest); LDS layout XOR-swizzled (stored unit = logical ^ (row&7)) with the
// inverse applied on the per-lane GLOBAL source address; ds_read_b128 frag
// reads are then bank-uniform. One barrier per iter; prefetch of tile t+1
// issued before compute of tile t.
// ---------------------------------------------------------------------------
__global__ __launch_bounds__(256) void attn_kernel(
    const u16* __restrict__ q_ws, const u16* __restrict__ k_ws,
    const u16* __restrict__ vt_ws, u16* __restrict__ x_ws)
{
    const int bid = blockIdx.x;
    const int orig = (bid & 7) * 32 + (bid >> 3);   // bijective XCD swizzle
    const int bh = orig >> 4;                       // 0..15
    const int qt128 = orig & 15;                    // 0..15
    const int b = bh >> 2, h = bh & 3;

    const int tid = threadIdx.x;
    const int wave = tid >> 6, lane = tid & 63;
    const int g = lane >> 4, ql = lane & 15;
    const int qbase = qt128 * 128 + wave * 32;

    const u16* qp = q_ws + ((size_t)bh * NSEQ + qbase) * DHEAD;
    const u16* kp = k_ws + (size_t)bh * NSEQ * DHEAD;
    const u16* vp = vt_ws + (size_t)bh * DHEAD * NSEQ;

    __shared__ u16 kt[2][64][64];            // [buf][m][d-units swizzled]
    __shared__ u16 vt[2][64][64];            // [buf][d][m-units swizzled]
    __shared__ u16 p_lds[4][2][16][72];      // per-wave P buffers

    // staging lane constants: lane -> (row-in-chunk, stored unit, logical unit)
    const int srow = lane >> 3;              // 0..7
    const int su_l = lane & 7;               // stored 16B-unit
    const int u_l  = su_l ^ srow;            // logical 16B-unit (inverse swizzle)
    const int swz  = ql & 7;                 // read-side swizzle key (row&7 == ql&7)

    // ---- load Q frags (once)
    short8 qf[2][2];
    #pragma unroll
    for (int qt = 0; qt < 2; qt++)
        #pragma unroll
        for (int kc = 0; kc < 2; kc++)
            qf[qt][kc] = *(const short8*)(qp + (size_t)(qt * 16 + ql) * DHEAD + kc * 32 + g * 8);

    float4v acc[2][4];
    #pragma unroll
    for (int qt = 0; qt < 2; qt++)
        #pragma unroll
        for (int t = 0; t < 4; t++) acc[qt][t] = (float4v){0.f, 0.f, 0.f, 0.f};
    float m0 = -INFINITY, m1 = -INFINITY, l0 = 0.f, l1 = 0.f;

    // ---- stage tile (64 keys at mb) into buffer bufi: 4 global_load_lds/wave
    #define STAGE(mb_, bufi_)                                                          \
        {                                                                              \
            _Pragma("unroll")                                                          \
            for (int i_ = 0; i_ < 2; i_++) {                                           \
                int row_ = wave * 16 + i_ * 8 + srow;                                  \
                __builtin_amdgcn_global_load_lds(                                      \
                    (const __attribute__((address_space(1))) unsigned int*)            \
                        (kp + (size_t)((mb_) + row_) * DHEAD + u_l * 8),               \
                    (__attribute__((address_space(3))) unsigned int*)                  \
                        &kt[bufi_][wave * 16 + i_ * 8][0],                             \
                    16, 0, 0);                                                         \
                __builtin_amdgcn_global_load_lds(                                      \
                    (const __attribute__((address_space(1))) unsigned int*)            \
                        (vp + (size_t)row_ * NSEQ + (mb_) + u_l * 8),                  \
                    (__attribute__((address_space(3))) unsigned int*)                  \
                        &vt[bufi_][wave * 16 + i_ * 8][0],                             \
                    16, 0, 0);                                                         \
            }                                                                          \
        }

    STAGE(0, 0);
    __syncthreads();

    int buf = 0;
    for (int t = 0; t < NSEQ / 64; t++) {
        const int mb = t * 64;
        if (t < NSEQ / 64 - 1) STAGE(mb + 64, buf ^ 1);

        // ---- S^T = K.Q^T from LDS (swizzled reads)
        float4v st[2][4];
        #pragma unroll
        for (int qt = 0; qt < 2; qt++)
            #pragma unroll
            for (int mt = 0; mt < 4; mt++) st[qt][mt] = (float4v){0.f, 0.f, 0.f, 0.f};
        #pragma unroll
        for (int mt = 0; mt < 4; mt++) {
            #pragma unroll
            for (int kc = 0; kc < 2; kc++) {
                short8 kf = *(const short8*)&kt[buf][mt * 16 + ql][((kc * 4 + g) ^ swz) * 8];
                st[0][mt] = __builtin_amdgcn_mfma_f32_16x16x32_bf16(kf, qf[0][kc], st[0][mt], 0, 0, 0);
                st[1][mt] = __builtin_amdgcn_mfma_f32_16x16x32_bf16(kf, qf[1][kc], st[1][mt], 0, 0, 0);
            }
        }

        // ---- tile max (scores in log2 units)
        float tmax0 = -INFINITY, tmax1 = -INFINITY;
        #pragma unroll
        for (int mt = 0; mt < 4; mt++)
            #pragma unroll
            for (int r = 0; r < 4; r++) {
                tmax0 = fmaxf(tmax0, st[0][mt][r]);
                tmax1 = fmaxf(tmax1, st[1][mt][r]);
            }
        tmax0 = fmaxf(tmax0, __shfl_xor(tmax0, 16, 64));
        tmax0 = fmaxf(tmax0, __shfl_xor(tmax0, 32, 64));
        tmax1 = fmaxf(tmax1, __shfl_xor(tmax1, 16, 64));
        tmax1 = fmaxf(tmax1, __shfl_xor(tmax1, 32, 64));

        // ---- defer-max rescale (2^8 headroom)
        bool need = (tmax0 > m0 + 8.f) || (tmax1 > m1 + 8.f);
        if (__any(need)) {
            float mn0 = fmaxf(m0, tmax0), mn1 = fmaxf(m1, tmax1);
            float a0 = __builtin_amdgcn_exp2f(m0 - mn0);
            float a1 = __builtin_amdgcn_exp2f(m1 - mn1);
            #pragma unroll
            for (int tt = 0; tt < 4; tt++)
                #pragma unroll
                for (int r = 0; r < 4; r++) {
                    acc[0][tt][r] *= a0;
                    acc[1][tt][r] *= a1;
                }
            l0 *= a0; l1 *= a1;
            m0 = mn0; m1 = mn1;
        }

        // ---- P = exp2(S - m), row sums, P -> wave-private LDS (bf16)
        float ps0 = 0.f, ps1 = 0.f;
        #pragma unroll
        for (int mt = 0; mt < 4; mt++) {
            float p0[4], p1[4];
            #pragma unroll
            for (int r = 0; r < 4; r++) {
                p0[r] = __builtin_amdgcn_exp2f(st[0][mt][r] - m0);
                p1[r] = __builtin_amdgcn_exp2f(st[1][mt][r] - m1);
                ps0 += p0[r];
                ps1 += p1[r];
            }
            unsigned* d0p = (unsigned*)&p_lds[wave][0][ql][mt * 16 + g * 4];
            d0p[0] = pack2bf(p0[0], p0[1]);
            d0p[1] = pack2bf(p0[2], p0[3]);
            unsigned* d1p = (unsigned*)&p_lds[wave][1][ql][mt * 16 + g * 4];
            d1p[0] = pack2bf(p1[0], p1[1]);
            d1p[1] = pack2bf(p1[2], p1[3]);
        }
        ps0 += __shfl_xor(ps0, 16, 64);
        ps0 += __shfl_xor(ps0, 32, 64);
        ps1 += __shfl_xor(ps1, 16, 64);
        ps1 += __shfl_xor(ps1, 32, 64);
        l0 += ps0; l1 += ps1;

        // ---- PV: x^T[d][q] += V^T[d][m] * P^T[m][q] from LDS
        #pragma unroll
        for (int kc = 0; kc < 2; kc++) {
            short8 pf0 = *(const short8*)&p_lds[wave][0][ql][kc * 32 + g * 8];
            short8 pf1 = *(const short8*)&p_lds[wave][1][ql][kc * 32 + g * 8];
            #pragma unroll
            for (int tt = 0; tt < 4; tt++) {
                short8 vf = *(const short8*)&vt[buf][tt * 16 + ql][((kc * 4 + g) ^ swz) * 8];
                acc[0][tt] = __builtin_amdgcn_mfma_f32_16x16x32_bf16(vf, pf0, acc[0][tt], 0, 0, 0);
                acc[1][tt] = __builtin_amdgcn_mfma_f32_16x16x32_bf16(vf, pf1, acc[1][tt], 0, 0, 0);
            }
        }
        __syncthreads();
        buf ^= 1;
    }
    #undef STAGE

    float inv0 = 1.f / l0, inv1 = 1.f / l1;
    #pragma unroll
    for (int qt = 0; qt < 2; qt++) {
        float inv = qt ? inv1 : inv0;
        #pragma unroll
        for (int t = 0; t < 4; t++)
            #pragma unroll
            for (int r = 0; r < 4; r++) {
                int d = t * 16 + g * 4 + r;
                int c = d * NH + h;
                x_ws[((size_t)b * DMODEL + c) * NSEQ + qbase + qt * 16 + ql] = f2bf(acc[qt][t][r] * inv);
            }
    }
}

// ---------------------------------------------------------------------------
// Output projection (unchanged from round 2).
// ---------------------------------------------------------------------------
__global__ __launch_bounds__(256) void proj_out_kernel(
    const u16* __restrict__ xw, const float* __restrict__ wm,
    const float* __restrict__ bm, float* __restrict__ out)
{
    const int nt0 = blockIdx.x, ot = blockIdx.y, b = blockIdx.z;
    const u16* X = xw + (size_t)b * DMODEL * NSEQ;

    const int tid = threadIdx.x;
    const int wave = tid >> 6, lane = tid & 63;
    const int g = lane >> 4, ql = lane & 15;

    __shared__ u16 xt[64][72];
    __shared__ u16 wt[64][72];

    float4v acc[4];
    #pragma unroll
    for (int i = 0; i < 4; i++) acc[i] = (float4v){0.f, 0.f, 0.f, 0.f};

    const int obase = ot * 64, nbase = nt0 * 64;

    for (int c0 = 0; c0 < DMODEL; c0 += 64) {
        #pragma unroll
        for (int i = 0; i < 2; i++) {            // X chunk: 64c x 64n bf16, 16B loads
            int e = tid + i * 256;
            int c = e >> 3, n8 = (e & 7) * 8;
            short8 xv8 = *(const short8*)&X[(size_t)(c0 + c) * NSEQ + nbase + n8];
            #pragma unroll
            for (int j = 0; j < 8; j++) xt[n8 + j][c] = (u16)xv8[j];
        }
        #pragma unroll
        for (int i = 0; i < 4; i++) {            // W chunk: 64o x 64c fp32, float4
            int e = tid + i * 256;
            int orow = e >> 4, c4 = (e & 15) * 4;
            float4v wv4 = *(const float4v*)&wm[(size_t)(obase + orow) * DMODEL + c0 + c4];
            unsigned* dst = (unsigned*)&wt[orow][c4];
            dst[0] = pack2bf(wv4[0], wv4[1]);
            dst[1] = pack2bf(wv4[2], wv4[3]);
        }
        __syncthreads();
        #pragma unroll
        for (int kc = 0; kc < 2; kc++) {
            short8 afrag = *(const short8*)&wt[wave * 16 + ql][kc * 32 + g * 8];
            #pragma unroll
            for (int nt = 0; nt < 4; nt++) {
                short8 bfrag = *(const short8*)&xt[nt * 16 + ql][kc * 32 + g * 8];
                acc[nt] = __builtin_amdgcn_mfma_f32_16x16x32_bf16(afrag, bfrag, acc[nt], 0, 0, 0);
            }
        }
        __syncthreads();
    }

    const int o0 = obase + wave * 16 + g * 4;
    #pragma unroll
    for (int nt = 0; nt < 4; nt++) {
        int n = nbase + nt * 16 + ql;
        #pragma unroll
        for (int r = 0; r < 4; r++) {
            int o = o0 + r;
            out[((size_t)b * DMODEL + o) * NSEQ + n] = acc[nt][r] + bm[o];
        }
    }
}

// ---------------------------------------------------------------------------
extern "C" void kernel_launch(void* const* d_in, const int* in_sizes, int n_in,
                              void* d_out, int out_size, void* d_ws, size_t ws_size,
                              hipStream_t stream)
{
    const float* query = (const float*)d_in[0];
    const float* key   = (const float*)d_in[1];
    const float* value = (const float*)d_in[2];
    const float* wq = (const float*)d_in[3];
    const float* bq = (const float*)d_in[4];
    const float* wk = (const float*)d_in[5];
    const float* bk = (const float*)d_in[6];
    const float* wv = (const float*)d_in[7];
    const float* bv = (const float*)d_in[8];
    const float* wm = (const float*)d_in[9];
    const float* bm = (const float*)d_in[10];
    float* out = (float*)d_out;

    char* ws = (char*)d_ws;
    const size_t SEG = (size_t)NB * NH * NSEQ * DHEAD * sizeof(u16);  // 4 MiB
    u16* q_ws  = (u16*)(ws);
    u16* k_ws  = (u16*)(ws + SEG);
    u16* vt_ws = (u16*)(ws + 2 * SEG);
    u16* x_ws  = (u16*)(ws + 3 * SEG);

    proj_qkv_kernel<<<dim3(32, 4, 12), 256, 0, stream>>>(
        query, key, value, wq, wk, wv, bq, bk, bv, q_ws, k_ws, vt_ws);
    attn_kernel<<<dim3(256), 256, 0, stream>>>(q_ws, k_ws, vt_ws, x_ws);
    proj_out_kernel<<<dim3(32, 4, NB), 256, 0, stream>>>(x_ws, wm, bm, out);
}

// Round 5
// 162.498 us; speedup vs baseline: 1.5538x; 1.0530x over previous
//
#include <hip/hip_runtime.h>
#include <hip/hip_bf16.h>

#define DMODEL 256
#define NSEQ   2048
#define NB     4
#define NH     4
#define DHEAD  64

typedef __attribute__((ext_vector_type(8))) short short8;
typedef __attribute__((ext_vector_type(4))) float float4v;
typedef __attribute__((ext_vector_type(2))) float float2v;
typedef __attribute__((ext_vector_type(2))) unsigned int uint2v;
typedef unsigned short u16;

#define AS1 __attribute__((address_space(1)))
#define AS3 __attribute__((address_space(3)))

static __device__ inline u16 f2bf(float f) {
    unsigned u = __builtin_bit_cast(unsigned, f);
    u += 0x7fffu + ((u >> 16) & 1u);   // round-to-nearest-even
    return (u16)(u >> 16);
}
static __device__ inline unsigned pk2(float a, float b) {   // v_cvt_pk_bf16_f32
    __hip_bfloat162 h = __float22bfloat162_rn(make_float2(a, b));
    unsigned r;
    __builtin_memcpy(&r, &h, 4);       // bit-copy (class type not bit_cast-able)
    return r;
}
static __device__ inline float max3f(float a, float b, float c) {
    return fmaxf(fmaxf(a, b), c);   // clang fuses to v_max3_f32
}
static __device__ inline float tmax16(const float4v* s) {
    float a = max3f(s[0][0], s[0][1], s[0][2]);
    float b = max3f(s[0][3], s[1][0], s[1][1]);
    float c = max3f(s[1][2], s[1][3], s[2][0]);
    float d = max3f(s[2][1], s[2][2], s[2][3]);
    float e = max3f(s[3][0], s[3][1], s[3][2]);
    float f = max3f(a, b, c);
    float g = max3f(d, e, s[3][3]);
    return fmaxf(f, g);
}

// ---------------------------------------------------------------------------
// convert_x: X fp32 [c][n] (12 planes: b*3+mode) -> xt_ws bf16 [plane][n][c].
// 64x64 tile transpose through swizzled LDS; coalesced read & write.
// ---------------------------------------------------------------------------
__global__ __launch_bounds__(256) void convert_x_kernel(
    const float* __restrict__ xq, const float* __restrict__ xk,
    const float* __restrict__ xv, u16* __restrict__ xt_ws)
{
    const int nt = blockIdx.x;     // 0..31
    const int ct = blockIdx.y;     // 0..3
    const int z  = blockIdx.z;     // 0..11
    const int b = z / 3, mode = z % 3;
    const float* X = ((mode == 0) ? xq : (mode == 1) ? xk : xv) + (size_t)b * DMODEL * NSEQ;
    u16* dst = xt_ws + (size_t)z * NSEQ * DMODEL;

    __shared__ u16 t[64][72];      // [n][c-units swizzled], rows 144 B
    const int tid = threadIdx.x;

    #pragma unroll
    for (int i = 0; i < 4; i++) {
        int e = tid + i * 256;
        int c = e >> 4;            // 0..63
        int n4 = (e & 15) * 4;
        float4v v = *(const float4v*)&X[(size_t)(ct * 64 + c) * NSEQ + nt * 64 + n4];
        #pragma unroll
        for (int j = 0; j < 4; j++) {
            int row = n4 + j;
            int fr = (row & 7) ^ ((row >> 3) & 7);
            t[row][(((c >> 3) ^ fr) << 3) + (c & 7)] = f2bf(v[j]);
        }
    }
    __syncthreads();
    #pragma unroll
    for (int i = 0; i < 4; i++) {
        int e = tid + i * 256;
        int n = e >> 4;            // 0..63
        int cb = (e & 15) * 4;     // 0..60
        int fr = (n & 7) ^ ((n >> 3) & 7);
        uint2v val = *(const uint2v*)&t[n][(((cb >> 3) ^ fr) << 3) + (cb & 7)];
        *(uint2v*)&dst[(size_t)(nt * 64 + n) * DMODEL + ct * 64 + cb] = val;
    }
}

// ---------------------------------------------------------------------------
// wpack: W fp32 -> wbf bf16 [4][256][256].
//  m=0..2 (wq,wk,wv): stored row sr holds source row (sr&~15)|perm(sr&15)
//    with perm(x) = ((x&3)<<2)|((x>>2)&3)  (epilogue coalescing trick).
//  m=3 (wm): wm_re[o][h*64+d] = wm[o][4d+h]  (head-major K for proj_out).
// ---------------------------------------------------------------------------
__global__ __launch_bounds__(256) void wpack_kernel(
    const float* __restrict__ wq, const float* __restrict__ wk,
    const float* __restrict__ wv, const float* __restrict__ wm,
    u16* __restrict__ wbf)
{
    const int sr = blockIdx.x, m = blockIdx.y, tcol = threadIdx.x;
    const float* W = (m == 0) ? wq : (m == 1) ? wk : (m == 2) ? wv : wm;
    float v;
    if (m < 3) {
        int og = (sr & ~15) | ((sr & 3) << 2) | ((sr >> 2) & 3);
        v = W[(size_t)og * DMODEL + tcol];
    } else {
        int c = ((tcol & 63) << 2) | (tcol >> 6);
        v = W[(size_t)sr * DMODEL + c];
    }
    wbf[(size_t)m * 65536 + (size_t)sr * DMODEL + tcol] = f2bf(v);
}

// ---------------------------------------------------------------------------
// proj_qkv: C = Wbf @ Xt^T, both bf16, staged via global_load_lds (16B) with
// XOR swizzle (inverse on global source, forward on frag reads). 64x64 tile,
// BK=64, double-buffered. Epilogue identical to round 2/3 (perm in wbf).
// ---------------------------------------------------------------------------
__global__ __launch_bounds__(256) void proj_qkv_kernel(
    const u16* __restrict__ xt_ws, const u16* __restrict__ wbf,
    const float* __restrict__ bqp, const float* __restrict__ bkp, const float* __restrict__ bvp,
    u16* __restrict__ q_ws, u16* __restrict__ k_ws, u16* __restrict__ vt_ws)
{
    const int nt0 = blockIdx.x, ot = blockIdx.y, bz = blockIdx.z;
    const int b = bz / 3, mode = bz % 3;
    const float* BI = (mode == 0) ? bqp : (mode == 1) ? bkp : bvp;

    const int tid = threadIdx.x;
    const int wave = tid >> 6, lane = tid & 63;
    const int g = lane >> 4, ql = lane & 15;
    const int srow8 = lane >> 3, su = lane & 7;
    const int u_l = su ^ srow8;
    const int obase = ot * 64, nbase = nt0 * 64;

    const u16* Asrc = wbf + (size_t)mode * 65536;
    const u16* Bsrc = xt_ws + (size_t)bz * (NSEQ * DMODEL);

    __shared__ u16 at[2][64][64];
    __shared__ u16 bt[2][64][64];

    float4v acc[4];
    #pragma unroll
    for (int i = 0; i < 4; i++) acc[i] = (float4v){0.f, 0.f, 0.f, 0.f};

    #define PSTAGE(bufi_, c0_)                                                         \
        { _Pragma("unroll")                                                            \
          for (int p_ = 0; p_ < 2; p_++) {                                             \
            int rb_ = wave * 8 + p_ * 32;                                              \
            int row_ = rb_ + srow8;                                                    \
            __builtin_amdgcn_global_load_lds(                                          \
                (const AS1 unsigned int*)(Asrc + (size_t)(obase + row_) * DMODEL + (c0_) + u_l * 8), \
                (AS3 unsigned int*)&at[bufi_][rb_][0], 16, 0, 0);                      \
            __builtin_amdgcn_global_load_lds(                                          \
                (const AS1 unsigned int*)(Bsrc + (size_t)(nbase + row_) * DMODEL + (c0_) + u_l * 8), \
                (AS3 unsigned int*)&bt[bufi_][rb_][0], 16, 0, 0);                      \
          } }

    PSTAGE(0, 0)
    __syncthreads();
    int buf = 0;
    const int sw = ql & 7;
    #pragma unroll
    for (int t = 0; t < 4; t++) {
        if (t < 3) PSTAGE(buf ^ 1, (t + 1) * 64)
        #pragma unroll
        for (int kc = 0; kc < 2; kc++) {
            short8 afrag = *(const short8*)&at[buf][wave * 16 + ql][(((kc * 4 + g) ^ sw)) * 8];
            #pragma unroll
            for (int nt = 0; nt < 4; nt++) {
                short8 bfrag = *(const short8*)&bt[buf][nt * 16 + ql][(((kc * 4 + g) ^ sw)) * 8];
                acc[nt] = __builtin_amdgcn_mfma_f32_16x16x32_bf16(afrag, bfrag, acc[nt], 0, 0, 0);
            }
        }
        __syncthreads();
        buf ^= 1;
    }
    #undef PSTAGE

    // epilogue: lane rows r=0..3 -> o = obase + wave*16 + 4r + g  (perm in wbf)
    const int h = g;
    const int d0 = (obase + wave * 16) >> 2;
    float bias[4];
    #pragma unroll
    for (int r = 0; r < 4; r++) bias[r] = BI[obase + wave * 16 + 4 * r + g];

    #pragma unroll
    for (int nt = 0; nt < 4; nt++) {
        int n = nbase + nt * 16 + ql;
        float v[4];
        #pragma unroll
        for (int r = 0; r < 4; r++) v[r] = acc[nt][r] + bias[r];
        if (mode == 0) {
            #pragma unroll
            for (int r = 0; r < 4; r++) v[r] *= 0.18033688011112042f;  // 0.125*log2(e)
            uint2v pk = {pk2(v[0], v[1]), pk2(v[2], v[3])};
            *(uint2v*)&q_ws[((size_t)(b * NH + h) * NSEQ + n) * DHEAD + d0] = pk;
        } else if (mode == 1) {
            uint2v pk = {pk2(v[0], v[1]), pk2(v[2], v[3])};
            *(uint2v*)&k_ws[((size_t)(b * NH + h) * NSEQ + n) * DHEAD + d0] = pk;
        } else {
            #pragma unroll
            for (int r = 0; r < 4; r++)
                vt_ws[((size_t)(b * NH + h) * DHEAD + d0 + r) * NSEQ + n] = f2bf(v[r]);
        }
    }
}

// ---------------------------------------------------------------------------
// Flash attention (structure = round 3; VALU diet + packed x_hs epilogue).
// ---------------------------------------------------------------------------
__global__ __launch_bounds__(256) void attn_kernel(
    const u16* __restrict__ q_ws, const u16* __restrict__ k_ws,
    const u16* __restrict__ vt_ws, u16* __restrict__ x_hs)
{
    const int bid = blockIdx.x;
    const int orig = (bid & 7) * 32 + (bid >> 3);   // bijective XCD swizzle
    const int bh = orig >> 4;
    const int qt128 = orig & 15;
    const int tid = threadIdx.x;
    const int wave = tid >> 6, lane = tid & 63;
    const int g = lane >> 4, ql = lane & 15;
    const int qbase = qt128 * 128 + wave * 32;

    const u16* qp = q_ws + ((size_t)bh * NSEQ + qbase) * DHEAD;
    const u16* kp = k_ws + (size_t)bh * NSEQ * DHEAD;
    const u16* vp = vt_ws + (size_t)bh * DHEAD * NSEQ;

    __shared__ u16 kt[2][64][64];
    __shared__ u16 vt[2][64][64];
    __shared__ u16 p_lds[4][2][16][72];

    const int srow = lane >> 3;
    const int su_l = lane & 7;
    const int u_l  = su_l ^ srow;
    const int swz  = ql & 7;

    short8 qf[2][2];
    #pragma unroll
    for (int qt = 0; qt < 2; qt++)
        #pragma unroll
        for (int kc = 0; kc < 2; kc++)
            qf[qt][kc] = *(const short8*)(qp + (size_t)(qt * 16 + ql) * DHEAD + kc * 32 + g * 8);

    float4v acc[2][4];
    #pragma unroll
    for (int qt = 0; qt < 2; qt++)
        #pragma unroll
        for (int t = 0; t < 4; t++) acc[qt][t] = (float4v){0.f, 0.f, 0.f, 0.f};
    float m0 = -INFINITY, m1 = -INFINITY, l0 = 0.f, l1 = 0.f;

    #define STAGE(mb_, bufi_)                                                          \
        {                                                                              \
            _Pragma("unroll")                                                          \
            for (int i_ = 0; i_ < 2; i_++) {                                           \
                int row_ = wave * 16 + i_ * 8 + srow;                                  \
                __builtin_amdgcn_global_load_lds(                                      \
                    (const AS1 unsigned int*)(kp + (size_t)((mb_) + row_) * DHEAD + u_l * 8), \
                    (AS3 unsigned int*)&kt[bufi_][wave * 16 + i_ * 8][0], 16, 0, 0);   \
                __builtin_amdgcn_global_load_lds(                                      \
                    (const AS1 unsigned int*)(vp + (size_t)row_ * NSEQ + (mb_) + u_l * 8), \
                    (AS3 unsigned int*)&vt[bufi_][wave * 16 + i_ * 8][0], 16, 0, 0);   \
            }                                                                          \
        }

    STAGE(0, 0);
    __syncthreads();

    int buf = 0;
    for (int t = 0; t < NSEQ / 64; t++) {
        const int mb = t * 64;
        if (t < NSEQ / 64 - 1) STAGE(mb + 64, buf ^ 1);

        // ---- S^T = K.Q^T from LDS
        float4v st[2][4];
        #pragma unroll
        for (int qt = 0; qt < 2; qt++)
            #pragma unroll
            for (int mt = 0; mt < 4; mt++) st[qt][mt] = (float4v){0.f, 0.f, 0.f, 0.f};
        #pragma unroll
        for (int mt = 0; mt < 4; mt++) {
            #pragma unroll
            for (int kc = 0; kc < 2; kc++) {
                short8 kf = *(const short8*)&kt[buf][mt * 16 + ql][((kc * 4 + g) ^ swz) * 8];
                st[0][mt] = __builtin_amdgcn_mfma_f32_16x16x32_bf16(kf, qf[0][kc], st[0][mt], 0, 0, 0);
                st[1][mt] = __builtin_amdgcn_mfma_f32_16x16x32_bf16(kf, qf[1][kc], st[1][mt], 0, 0, 0);
            }
        }

        // ---- tile max (max3 trees) + cross-lane
        float tmax0 = tmax16(&st[0][0]);
        float tmax1 = tmax16(&st[1][0]);
        tmax0 = fmaxf(tmax0, __shfl_xor(tmax0, 16, 64));
        tmax0 = fmaxf(tmax0, __shfl_xor(tmax0, 32, 64));
        tmax1 = fmaxf(tmax1, __shfl_xor(tmax1, 16, 64));
        tmax1 = fmaxf(tmax1, __shfl_xor(tmax1, 32, 64));

        // ---- defer-max rescale (2^8 headroom)
        bool need = (tmax0 > m0 + 8.f) || (tmax1 > m1 + 8.f);
        if (__any(need)) {
            float mn0 = fmaxf(m0, tmax0), mn1 = fmaxf(m1, tmax1);
            float a0 = __builtin_amdgcn_exp2f(m0 - mn0);
            float a1 = __builtin_amdgcn_exp2f(m1 - mn1);
            #pragma unroll
            for (int tt = 0; tt < 4; tt++)
                #pragma unroll
                for (int r = 0; r < 4; r++) {
                    acc[0][tt][r] *= a0;
                    acc[1][tt][r] *= a1;
                }
            l0 *= a0; l1 *= a1;
            m0 = mn0; m1 = mn1;
        }

        // ---- P = exp2(S - m): cvt_pk packing, float2 paired sums, b64 stores
        float2v s0v = {0.f, 0.f}, s1v = {0.f, 0.f};
        #pragma unroll
        for (int mt = 0; mt < 4; mt++) {
            float p00 = __builtin_amdgcn_exp2f(st[0][mt][0] - m0);
            float p01 = __builtin_amdgcn_exp2f(st[0][mt][1] - m0);
            float p02 = __builtin_amdgcn_exp2f(st[0][mt][2] - m0);
            float p03 = __builtin_amdgcn_exp2f(st[0][mt][3] - m0);
            s0v += (float2v){p00, p01};
            s0v += (float2v){p02, p03};
            *(uint2v*)&p_lds[wave][0][ql][mt * 16 + g * 4] = (uint2v){pk2(p00, p01), pk2(p02, p03)};
            float p10 = __builtin_amdgcn_exp2f(st[1][mt][0] - m1);
            float p11 = __builtin_amdgcn_exp2f(st[1][mt][1] - m1);
            float p12 = __builtin_amdgcn_exp2f(st[1][mt][2] - m1);
            float p13 = __builtin_amdgcn_exp2f(st[1][mt][3] - m1);
            s1v += (float2v){p10, p11};
            s1v += (float2v){p12, p13};
            *(uint2v*)&p_lds[wave][1][ql][mt * 16 + g * 4] = (uint2v){pk2(p10, p11), pk2(p12, p13)};
        }
        float ps0 = s0v[0] + s0v[1], ps1 = s1v[0] + s1v[1];
        ps0 += __shfl_xor(ps0, 16, 64);
        ps0 += __shfl_xor(ps0, 32, 64);
        ps1 += __shfl_xor(ps1, 16, 64);
        ps1 += __shfl_xor(ps1, 32, 64);
        l0 += ps0; l1 += ps1;

        // ---- PV
        #pragma unroll
        for (int kc = 0; kc < 2; kc++) {
            short8 pf0 = *(const short8*)&p_lds[wave][0][ql][kc * 32 + g * 8];
            short8 pf1 = *(const short8*)&p_lds[wave][1][ql][kc * 32 + g * 8];
            #pragma unroll
            for (int tt = 0; tt < 4; tt++) {
                short8 vf = *(const short8*)&vt[buf][tt * 16 + ql][((kc * 4 + g) ^ swz) * 8];
                acc[0][tt] = __builtin_amdgcn_mfma_f32_16x16x32_bf16(vf, pf0, acc[0][tt], 0, 0, 0);
                acc[1][tt] = __builtin_amdgcn_mfma_f32_16x16x32_bf16(vf, pf1, acc[1][tt], 0, 0, 0);
            }
        }
        __syncthreads();
        buf ^= 1;
    }
    #undef STAGE

    // ---- epilogue: x_hs[bh][n][d] bf16, packed 8B stores
    float inv0 = 1.f / l0, inv1 = 1.f / l1;
    #pragma unroll
    for (int qt = 0; qt < 2; qt++) {
        float inv = qt ? inv1 : inv0;
        u16* xrow = x_hs + ((size_t)bh * NSEQ + qbase + qt * 16 + ql) * DHEAD;
        #pragma unroll
        for (int t = 0; t < 4; t++) {
            uint2v pk = {pk2(acc[qt][t][0] * inv, acc[qt][t][1] * inv),
                         pk2(acc[qt][t][2] * inv, acc[qt][t][3] * inv)};
            *(uint2v*)&xrow[t * 16 + g * 4] = pk;
        }
    }
}

// ---------------------------------------------------------------------------
// proj_out: out = Wm_re @ x_hs + bm.  K-dim = (h,d); both operands bf16
// linear; same staging/MFMA structure as proj_qkv; fp32 epilogue.
// ---------------------------------------------------------------------------
__global__ __launch_bounds__(256) void proj_out_kernel(
    const u16* __restrict__ x_hs, const u16* __restrict__ wbf,
    const float* __restrict__ bm, float* __restrict__ out)
{
    const int nt0 = blockIdx.x, ot = blockIdx.y, b = blockIdx.z;

    const int tid = threadIdx.x;
    const int wave = tid >> 6, lane = tid & 63;
    const int g = lane >> 4, ql = lane & 15;
    const int srow8 = lane >> 3, su = lane & 7;
    const int u_l = su ^ srow8;
    const int obase = ot * 64, nbase = nt0 * 64;

    const u16* Asrc = wbf + (size_t)3 * 65536;

    __shared__ u16 at[2][64][64];
    __shared__ u16 bt[2][64][64];

    float4v acc[4];
    #pragma unroll
    for (int i = 0; i < 4; i++) acc[i] = (float4v){0.f, 0.f, 0.f, 0.f};

    #define OSTAGE(bufi_, c0_)                                                         \
        { _Pragma("unroll")                                                            \
          for (int p_ = 0; p_ < 2; p_++) {                                             \
            int rb_ = wave * 8 + p_ * 32;                                              \
            int row_ = rb_ + srow8;                                                    \
            __builtin_amdgcn_global_load_lds(                                          \
                (const AS1 unsigned int*)(Asrc + (size_t)(obase + row_) * DMODEL + (c0_) + u_l * 8), \
                (AS3 unsigned int*)&at[bufi_][rb_][0], 16, 0, 0);                      \
            __builtin_amdgcn_global_load_lds(                                          \
                (const AS1 unsigned int*)(x_hs + ((size_t)(b * NH + ((c0_) >> 6)) * NSEQ + nbase + row_) * DHEAD + u_l * 8), \
                (AS3 unsigned int*)&bt[bufi_][rb_][0], 16, 0, 0);                      \
          } }

    OSTAGE(0, 0)
    __syncthreads();
    int buf = 0;
    const int sw = ql & 7;
    #pragma unroll
    for (int t = 0; t < 4; t++) {
        if (t < 3) OSTAGE(buf ^ 1, (t + 1) * 64)
        #pragma unroll
        for (int kc = 0; kc < 2; kc++) {
            short8 afrag = *(const short8*)&at[buf][wave * 16 + ql][(((kc * 4 + g) ^ sw)) * 8];
            #pragma unroll
            for (int nt = 0; nt < 4; nt++) {
                short8 bfrag = *(const short8*)&bt[buf][nt * 16 + ql][(((kc * 4 + g) ^ sw)) * 8];
                acc[nt] = __builtin_amdgcn_mfma_f32_16x16x32_bf16(afrag, bfrag, acc[nt], 0, 0, 0);
            }
        }
        __syncthreads();
        buf ^= 1;
    }
    #undef OSTAGE

    const int o0 = obase + wave * 16 + g * 4;
    #pragma unroll
    for (int nt = 0; nt < 4; nt++) {
        int n = nbase + nt * 16 + ql;
        #pragma unroll
        for (int r = 0; r < 4; r++) {
            int o = o0 + r;
            out[((size_t)b * DMODEL + o) * NSEQ + n] = acc[nt][r] + bm[o];
        }
    }
}

// ---------------------------------------------------------------------------
extern "C" void kernel_launch(void* const* d_in, const int* in_sizes, int n_in,
                              void* d_out, int out_size, void* d_ws, size_t ws_size,
                              hipStream_t stream)
{
    const float* query = (const float*)d_in[0];
    const float* key   = (const float*)d_in[1];
    const float* value = (const float*)d_in[2];
    const float* wq = (const float*)d_in[3];
    const float* bq = (const float*)d_in[4];
    const float* wk = (const float*)d_in[5];
    const float* bk = (const float*)d_in[6];
    const float* wv = (const float*)d_in[7];
    const float* bv = (const float*)d_in[8];
    const float* wm = (const float*)d_in[9];
    const float* bm = (const float*)d_in[10];
    float* out = (float*)d_out;

    char* ws = (char*)d_ws;
    const size_t SEG = (size_t)NB * NH * NSEQ * DHEAD * sizeof(u16);      // 4 MiB
    u16* q_ws  = (u16*)(ws);
    u16* k_ws  = (u16*)(ws + SEG);
    u16* vt_ws = (u16*)(ws + 2 * SEG);
    u16* x_hs  = (u16*)(ws + 3 * SEG);
    u16* xt_ws = (u16*)(ws + 4 * SEG);                                    // 12 MiB
    u16* wbf   = (u16*)(ws + 4 * SEG + (size_t)12 * NSEQ * DMODEL * sizeof(u16));

    convert_x_kernel<<<dim3(32, 4, 12), 256, 0, stream>>>(query, key, value, xt_ws);
    wpack_kernel<<<dim3(256, 4), 256, 0, stream>>>(wq, wk, wv, wm, wbf);
    proj_qkv_kernel<<<dim3(32, 4, 12), 256, 0, stream>>>(
        xt_ws, wbf, bq, bk, bv, q_ws, k_ws, vt_ws);
    attn_kernel<<<dim3(256), 256, 0, stream>>>(q_ws, k_ws, vt_ws, x_hs);
    proj_out_kernel<<<dim3(32, 4, NB), 256, 0, stream>>>(x_hs, wbf, bm, out);
}

// Round 6
// 155.251 us; speedup vs baseline: 1.6264x; 1.0467x over previous
//
#include <hip/hip_runtime.h>
#include <hip/hip_bf16.h>

#define DMODEL 256
#define NSEQ   2048
#define NB     4
#define NH     4
#define DHEAD  64

typedef __attribute__((ext_vector_type(8))) short short8;
typedef __attribute__((ext_vector_type(4))) float float4v;
typedef __attribute__((ext_vector_type(2))) unsigned int uint2v;
typedef unsigned short u16;

#define AS1 __attribute__((address_space(1)))
#define AS3 __attribute__((address_space(3)))

static __device__ inline u16 f2bf(float f) {
    unsigned u = __builtin_bit_cast(unsigned, f);
    u += 0x7fffu + ((u >> 16) & 1u);   // round-to-nearest-even
    return (u16)(u >> 16);
}
static __device__ inline unsigned pack2bf(float a, float b) {
    return (unsigned)f2bf(a) | ((unsigned)f2bf(b) << 16);
}
static __device__ inline float max3f(float a, float b, float c) {
    return fmaxf(fmaxf(a, b), c);   // clang fuses to v_max3_f32
}
static __device__ inline float tmax16(const float4v* s) {
    float a = max3f(s[0][0], s[0][1], s[0][2]);
    float b = max3f(s[0][3], s[1][0], s[1][1]);
    float c = max3f(s[1][2], s[1][3], s[2][0]);
    float d = max3f(s[2][1], s[2][2], s[2][3]);
    float e = max3f(s[3][0], s[3][1], s[3][2]);
    float f = max3f(a, b, c);
    float g = max3f(d, e, s[3][3]);
    return fmaxf(f, g);
}

// ---------------------------------------------------------------------------
// prep kernel: merged convert_x + wpack (one dispatch).
//  blocks [0,1536): X fp32 [c][n] -> xt_ws bf16 [plane][n][c] (transpose).
//  blocks [1536,2560): W fp32 -> wbf bf16 [4][256][256] (permuted rows).
// ---------------------------------------------------------------------------
__global__ __launch_bounds__(256) void prep_kernel(
    const float* __restrict__ xq, const float* __restrict__ xk,
    const float* __restrict__ xv,
    const float* __restrict__ wq, const float* __restrict__ wk,
    const float* __restrict__ wv, const float* __restrict__ wm,
    u16* __restrict__ xt_ws, u16* __restrict__ wbf)
{
    const int bid = blockIdx.x;
    const int tid = threadIdx.x;

    if (bid >= 1536) {                  // ---- wpack part
        const int id = bid - 1536;
        const int sr = id & 255, m = id >> 8;
        const float* W = (m == 0) ? wq : (m == 1) ? wk : (m == 2) ? wv : wm;
        float v;
        if (m < 3) {
            int og = (sr & ~15) | ((sr & 3) << 2) | ((sr >> 2) & 3);
            v = W[(size_t)og * DMODEL + tid];
        } else {
            int c = ((tid & 63) << 2) | (tid >> 6);
            v = W[(size_t)sr * DMODEL + c];
        }
        wbf[(size_t)m * 65536 + (size_t)sr * DMODEL + tid] = f2bf(v);
        return;
    }

    // ---- convert_x part
    const int nt = bid & 31;
    const int ct = (bid >> 5) & 3;
    const int z  = bid >> 7;            // 0..11
    const int b = z / 3, mode = z % 3;
    const float* X = ((mode == 0) ? xq : (mode == 1) ? xk : xv) + (size_t)b * DMODEL * NSEQ;
    u16* dst = xt_ws + (size_t)z * NSEQ * DMODEL;

    __shared__ u16 t[64][72];

    #pragma unroll
    for (int i = 0; i < 4; i++) {
        int e = tid + i * 256;
        int c = e >> 4;
        int n4 = (e & 15) * 4;
        float4v v = *(const float4v*)&X[(size_t)(ct * 64 + c) * NSEQ + nt * 64 + n4];
        #pragma unroll
        for (int j = 0; j < 4; j++) {
            int row = n4 + j;
            int fr = (row & 7) ^ ((row >> 3) & 7);
            t[row][(((c >> 3) ^ fr) << 3) + (c & 7)] = f2bf(v[j]);
        }
    }
    __syncthreads();
    #pragma unroll
    for (int i = 0; i < 4; i++) {
        int e = tid + i * 256;
        int n = e >> 4;
        int cb = (e & 15) * 4;
        int fr = (n & 7) ^ ((n >> 3) & 7);
        uint2v val = *(const uint2v*)&t[n][(((cb >> 3) ^ fr) << 3) + (cb & 7)];
        *(uint2v*)&dst[(size_t)(nt * 64 + n) * DMODEL + ct * 64 + cb] = val;
    }
}

// ---------------------------------------------------------------------------
// proj_qkv: C = Wbf @ Xt^T, both bf16, staged via global_load_lds (16B) with
// XOR swizzle. 64x64 tile, BK=64, double-buffered.
// ---------------------------------------------------------------------------
__global__ __launch_bounds__(256) void proj_qkv_kernel(
    const u16* __restrict__ xt_ws, const u16* __restrict__ wbf,
    const float* __restrict__ bqp, const float* __restrict__ bkp, const float* __restrict__ bvp,
    u16* __restrict__ q_ws, u16* __restrict__ k_ws, u16* __restrict__ vt_ws)
{
    const int nt0 = blockIdx.x, ot = blockIdx.y, bz = blockIdx.z;
    const int b = bz / 3, mode = bz % 3;
    const float* BI = (mode == 0) ? bqp : (mode == 1) ? bkp : bvp;

    const int tid = threadIdx.x;
    const int wave = tid >> 6, lane = tid & 63;
    const int g = lane >> 4, ql = lane & 15;
    const int srow8 = lane >> 3, su = lane & 7;
    const int u_l = su ^ srow8;
    const int obase = ot * 64, nbase = nt0 * 64;

    const u16* Asrc = wbf + (size_t)mode * 65536;
    const u16* Bsrc = xt_ws + (size_t)bz * (NSEQ * DMODEL);

    __shared__ u16 at[2][64][64];
    __shared__ u16 bt[2][64][64];

    float4v acc[4];
    #pragma unroll
    for (int i = 0; i < 4; i++) acc[i] = (float4v){0.f, 0.f, 0.f, 0.f};

    #define PSTAGE(bufi_, c0_)                                                         \
        { _Pragma("unroll")                                                            \
          for (int p_ = 0; p_ < 2; p_++) {                                             \
            int rb_ = wave * 8 + p_ * 32;                                              \
            int row_ = rb_ + srow8;                                                    \
            __builtin_amdgcn_global_load_lds(                                          \
                (const AS1 unsigned int*)(Asrc + (size_t)(obase + row_) * DMODEL + (c0_) + u_l * 8), \
                (AS3 unsigned int*)&at[bufi_][rb_][0], 16, 0, 0);                      \
            __builtin_amdgcn_global_load_lds(                                          \
                (const AS1 unsigned int*)(Bsrc + (size_t)(nbase + row_) * DMODEL + (c0_) + u_l * 8), \
                (AS3 unsigned int*)&bt[bufi_][rb_][0], 16, 0, 0);                      \
          } }

    PSTAGE(0, 0)
    __syncthreads();
    int buf = 0;
    const int sw = ql & 7;
    #pragma unroll
    for (int t = 0; t < 4; t++) {
        if (t < 3) PSTAGE(buf ^ 1, (t + 1) * 64)
        #pragma unroll
        for (int kc = 0; kc < 2; kc++) {
            short8 afrag = *(const short8*)&at[buf][wave * 16 + ql][(((kc * 4 + g) ^ sw)) * 8];
            #pragma unroll
            for (int nt = 0; nt < 4; nt++) {
                short8 bfrag = *(const short8*)&bt[buf][nt * 16 + ql][(((kc * 4 + g) ^ sw)) * 8];
                acc[nt] = __builtin_amdgcn_mfma_f32_16x16x32_bf16(afrag, bfrag, acc[nt], 0, 0, 0);
            }
        }
        __syncthreads();
        buf ^= 1;
    }
    #undef PSTAGE

    // epilogue: lane rows r=0..3 -> o = obase + wave*16 + 4r + g  (perm in wbf)
    const int h = g;
    const int d0 = (obase + wave * 16) >> 2;
    float bias[4];
    #pragma unroll
    for (int r = 0; r < 4; r++) bias[r] = BI[obase + wave * 16 + 4 * r + g];

    #pragma unroll
    for (int nt = 0; nt < 4; nt++) {
        int n = nbase + nt * 16 + ql;
        float v[4];
        #pragma unroll
        for (int r = 0; r < 4; r++) v[r] = acc[nt][r] + bias[r];
        if (mode == 0) {
            #pragma unroll
            for (int r = 0; r < 4; r++) v[r] *= 0.18033688011112042f;  // 0.125*log2(e)
            uint2v pk = {pack2bf(v[0], v[1]), pack2bf(v[2], v[3])};
            *(uint2v*)&q_ws[((size_t)(b * NH + h) * NSEQ + n) * DHEAD + d0] = pk;
        } else if (mode == 1) {
            uint2v pk = {pack2bf(v[0], v[1]), pack2bf(v[2], v[3])};
            *(uint2v*)&k_ws[((size_t)(b * NH + h) * NSEQ + n) * DHEAD + d0] = pk;
        } else {
            #pragma unroll
            for (int r = 0; r < 4; r++)
                vt_ws[((size_t)(b * NH + h) * DHEAD + d0 + r) * NSEQ + n] = f2bf(v[r]);
        }
    }
}

// ---------------------------------------------------------------------------
// Flash attention v5: 8 waves x 16 q = 128 q/block, 256 blocks (1/CU,
// 2 waves/SIMD). K/V double-buffered via global_load_lds (1 each per wave),
// XOR-swizzled. Manual bf16 packing (round-3 proven). Defer-max softmax.
// ---------------------------------------------------------------------------
__global__ __launch_bounds__(512) void attn_kernel(
    const u16* __restrict__ q_ws, const u16* __restrict__ k_ws,
    const u16* __restrict__ vt_ws, u16* __restrict__ x_hs)
{
    const int bid = blockIdx.x;
    const int orig = (bid & 7) * 32 + (bid >> 3);   // bijective XCD swizzle
    const int bh = orig >> 4;
    const int qt128 = orig & 15;
    const int tid = threadIdx.x;
    const int wave = tid >> 6, lane = tid & 63;
    const int g = lane >> 4, ql = lane & 15;
    const int qbase = qt128 * 128 + wave * 16;

    const u16* qp = q_ws + ((size_t)bh * NSEQ + qbase) * DHEAD;
    const u16* kp = k_ws + (size_t)bh * NSEQ * DHEAD;
    const u16* vp = vt_ws + (size_t)bh * DHEAD * NSEQ;

    __shared__ u16 kt[2][64][64];
    __shared__ u16 vt[2][64][64];
    __shared__ u16 p_lds[8][16][72];

    const int srow = lane >> 3;          // 0..7
    const int su_l = lane & 7;
    const int u_l  = su_l ^ srow;
    const int swz  = ql & 7;

    // Q frags (16 q per wave)
    short8 qf[2];
    #pragma unroll
    for (int kc = 0; kc < 2; kc++)
        qf[kc] = *(const short8*)(qp + (size_t)ql * DHEAD + kc * 32 + g * 8);

    float4v acc[4];
    #pragma unroll
    for (int t = 0; t < 4; t++) acc[t] = (float4v){0.f, 0.f, 0.f, 0.f};
    float mrun = -INFINITY, lrun = 0.f;

    // each wave stages 8 rows of kt and 8 rows of vt (1 gload each)
    #define STAGE(mb_, bufi_)                                                          \
        {                                                                              \
            int row_ = wave * 8 + srow;                                                \
            __builtin_amdgcn_global_load_lds(                                          \
                (const AS1 unsigned int*)(kp + (size_t)((mb_) + row_) * DHEAD + u_l * 8), \
                (AS3 unsigned int*)&kt[bufi_][wave * 8][0], 16, 0, 0);                 \
            __builtin_amdgcn_global_load_lds(                                          \
                (const AS1 unsigned int*)(vp + (size_t)row_ * NSEQ + (mb_) + u_l * 8), \
                (AS3 unsigned int*)&vt[bufi_][wave * 8][0], 16, 0, 0);                 \
        }

    STAGE(0, 0);
    __syncthreads();

    int buf = 0;
    for (int t = 0; t < NSEQ / 64; t++) {
        const int mb = t * 64;
        if (t < NSEQ / 64 - 1) STAGE(mb + 64, buf ^ 1);

        // ---- S^T = K.Q^T from LDS
        float4v st[4];
        #pragma unroll
        for (int mt = 0; mt < 4; mt++) st[mt] = (float4v){0.f, 0.f, 0.f, 0.f};
        #pragma unroll
        for (int mt = 0; mt < 4; mt++) {
            #pragma unroll
            for (int kc = 0; kc < 2; kc++) {
                short8 kf = *(const short8*)&kt[buf][mt * 16 + ql][((kc * 4 + g) ^ swz) * 8];
                st[mt] = __builtin_amdgcn_mfma_f32_16x16x32_bf16(kf, qf[kc], st[mt], 0, 0, 0);
            }
        }

        // ---- tile max + cross-lane
        float tmax = tmax16(&st[0]);
        tmax = fmaxf(tmax, __shfl_xor(tmax, 16, 64));
        tmax = fmaxf(tmax, __shfl_xor(tmax, 32, 64));

        // ---- defer-max rescale (2^8 headroom, scores in log2 units)
        if (__any(tmax > mrun + 8.f)) {
            float mnew = fmaxf(mrun, tmax);
            float a = __builtin_amdgcn_exp2f(mrun - mnew);
            #pragma unroll
            for (int tt = 0; tt < 4; tt++)
                #pragma unroll
                for (int r = 0; r < 4; r++) acc[tt][r] *= a;
            lrun *= a;
            mrun = mnew;
        }

        // ---- P = exp2(S - m), row sums, P -> wave-private LDS (bf16)
        float psum = 0.f;
        #pragma unroll
        for (int mt = 0; mt < 4; mt++) {
            float p0 = __builtin_amdgcn_exp2f(st[mt][0] - mrun);
            float p1 = __builtin_amdgcn_exp2f(st[mt][1] - mrun);
            float p2 = __builtin_amdgcn_exp2f(st[mt][2] - mrun);
            float p3 = __builtin_amdgcn_exp2f(st[mt][3] - mrun);
            psum += (p0 + p1) + (p2 + p3);
            *(uint2v*)&p_lds[wave][ql][mt * 16 + g * 4] = (uint2v){pack2bf(p0, p1), pack2bf(p2, p3)};
        }
        psum += __shfl_xor(psum, 16, 64);
        psum += __shfl_xor(psum, 32, 64);
        lrun += psum;

        // ---- PV: x^T[d][q] += V^T[d][m] * P^T[m][q]
        #pragma unroll
        for (int kc = 0; kc < 2; kc++) {
            short8 pf = *(const short8*)&p_lds[wave][ql][kc * 32 + g * 8];
            #pragma unroll
            for (int tt = 0; tt < 4; tt++) {
                short8 vf = *(const short8*)&vt[buf][tt * 16 + ql][((kc * 4 + g) ^ swz) * 8];
                acc[tt] = __builtin_amdgcn_mfma_f32_16x16x32_bf16(vf, pf, acc[tt], 0, 0, 0);
            }
        }
        __syncthreads();
        buf ^= 1;
    }
    #undef STAGE

    // ---- epilogue: x_hs[bh][n][d] bf16, packed 8B stores
    float inv = 1.f / lrun;
    u16* xrow = x_hs + ((size_t)bh * NSEQ + qbase + ql) * DHEAD;
    #pragma unroll
    for (int t = 0; t < 4; t++) {
        uint2v pk = {pack2bf(acc[t][0] * inv, acc[t][1] * inv),
                     pack2bf(acc[t][2] * inv, acc[t][3] * inv)};
        *(uint2v*)&xrow[t * 16 + g * 4] = pk;
    }
}

// ---------------------------------------------------------------------------
// proj_out: out = Wm_re @ x_hs + bm.  Same structure as proj_qkv.
// ---------------------------------------------------------------------------
__global__ __launch_bounds__(256) void proj_out_kernel(
    const u16* __restrict__ x_hs, const u16* __restrict__ wbf,
    const float* __restrict__ bm, float* __restrict__ out)
{
    const int nt0 = blockIdx.x, ot = blockIdx.y, b = blockIdx.z;

    const int tid = threadIdx.x;
    const int wave = tid >> 6, lane = tid & 63;
    const int g = lane >> 4, ql = lane & 15;
    const int srow8 = lane >> 3, su = lane & 7;
    const int u_l = su ^ srow8;
    const int obase = ot * 64, nbase = nt0 * 64;

    const u16* Asrc = wbf + (size_t)3 * 65536;

    __shared__ u16 at[2][64][64];
    __shared__ u16 bt[2][64][64];

    float4v acc[4];
    #pragma unroll
    for (int i = 0; i < 4; i++) acc[i] = (float4v){0.f, 0.f, 0.f, 0.f};

    #define OSTAGE(bufi_, c0_)                                                         \
        { _Pragma("unroll")                                                            \
          for (int p_ = 0; p_ < 2; p_++) {                                             \
            int rb_ = wave * 8 + p_ * 32;                                              \
            int row_ = rb_ + srow8;                                                    \
            __builtin_amdgcn_global_load_lds(                                          \
                (const AS1 unsigned int*)(Asrc + (size_t)(obase + row_) * DMODEL + (c0_) + u_l * 8), \
                (AS3 unsigned int*)&at[bufi_][rb_][0], 16, 0, 0);                      \
            __builtin_amdgcn_global_load_lds(                                          \
                (const AS1 unsigned int*)(x_hs + ((size_t)(b * NH + ((c0_) >> 6)) * NSEQ + nbase + row_) * DHEAD + u_l * 8), \
                (AS3 unsigned int*)&bt[bufi_][rb_][0], 16, 0, 0);                      \
          } }

    OSTAGE(0, 0)
    __syncthreads();
    int buf = 0;
    const int sw = ql & 7;
    #pragma unroll
    for (int t = 0; t < 4; t++) {
        if (t < 3) OSTAGE(buf ^ 1, (t + 1) * 64)
        #pragma unroll
        for (int kc = 0; kc < 2; kc++) {
            short8 afrag = *(const short8*)&at[buf][wave * 16 + ql][(((kc * 4 + g) ^ sw)) * 8];
            #pragma unroll
            for (int nt = 0; nt < 4; nt++) {
                short8 bfrag = *(const short8*)&bt[buf][nt * 16 + ql][(((kc * 4 + g) ^ sw)) * 8];
                acc[nt] = __builtin_amdgcn_mfma_f32_16x16x32_bf16(afrag, bfrag, acc[nt], 0, 0, 0);
            }
        }
        __syncthreads();
        buf ^= 1;
    }
    #undef OSTAGE

    const int o0 = obase + wave * 16 + g * 4;
    #pragma unroll
    for (int nt = 0; nt < 4; nt++) {
        int n = nbase + nt * 16 + ql;
        #pragma unroll
        for (int r = 0; r < 4; r++) {
            int o = o0 + r;
            out[((size_t)b * DMODEL + o) * NSEQ + n] = acc[nt][r] + bm[o];
        }
    }
}

// ---------------------------------------------------------------------------
extern "C" void kernel_launch(void* const* d_in, const int* in_sizes, int n_in,
                              void* d_out, int out_size, void* d_ws, size_t ws_size,
                              hipStream_t stream)
{
    const float* query = (const float*)d_in[0];
    const float* key   = (const float*)d_in[1];
    const float* value = (const float*)d_in[2];
    const float* wq = (const float*)d_in[3];
    const float* bq = (const float*)d_in[4];
    const float* wk = (const float*)d_in[5];
    const float* bk = (const float*)d_in[6];
    const float* wv = (const float*)d_in[7];
    const float* bv = (const float*)d_in[8];
    const float* wm = (const float*)d_in[9];
    const float* bm = (const float*)d_in[10];
    float* out = (float*)d_out;

    char* ws = (char*)d_ws;
    const size_t SEG = (size_t)NB * NH * NSEQ * DHEAD * sizeof(u16);      // 4 MiB
    u16* q_ws  = (u16*)(ws);
    u16* k_ws  = (u16*)(ws + SEG);
    u16* vt_ws = (u16*)(ws + 2 * SEG);
    u16* x_hs  = (u16*)(ws + 3 * SEG);
    u16* xt_ws = (u16*)(ws + 4 * SEG);                                    // 12 MiB
    u16* wbf   = (u16*)(ws + 4 * SEG + (size_t)12 * NSEQ * DMODEL * sizeof(u16));

    prep_kernel<<<dim3(2560), 256, 0, stream>>>(
        query, key, value, wq, wk, wv, wm, xt_ws, wbf);
    proj_qkv_kernel<<<dim3(32, 4, 12), 256, 0, stream>>>(
        xt_ws, wbf, bq, bk, bv, q_ws, k_ws, vt_ws);
    attn_kernel<<<dim3(256), 512, 0, stream>>>(q_ws, k_ws, vt_ws, x_hs);
    proj_out_kernel<<<dim3(32, 4, NB), 256, 0, stream>>>(x_hs, wbf, bm, out);
}

// Round 7
// 146.410 us; speedup vs baseline: 1.7246x; 1.0604x over previous
//
#include <hip/hip_runtime.h>
#include <hip/hip_bf16.h>

#define DMODEL 256
#define NSEQ   2048
#define NB     4
#define NH     4
#define DHEAD  64

typedef __attribute__((ext_vector_type(8))) short short8;
typedef __attribute__((ext_vector_type(4))) float float4v;
typedef __attribute__((ext_vector_type(2))) float float2v;
typedef __attribute__((ext_vector_type(2))) unsigned int uint2v;
typedef unsigned short u16;

#define AS1 __attribute__((address_space(1)))
#define AS3 __attribute__((address_space(3)))

static __device__ inline u16 f2bf(float f) {
    unsigned u = __builtin_bit_cast(unsigned, f);
    u += 0x7fffu + ((u >> 16) & 1u);   // round-to-nearest-even
    return (u16)(u >> 16);
}
static __device__ inline unsigned pack2bf(float a, float b) {
    return (unsigned)f2bf(a) | ((unsigned)f2bf(b) << 16);
}
static __device__ inline float max3f(float a, float b, float c) {
    return fmaxf(fmaxf(a, b), c);   // clang fuses to v_max3_f32
}
static __device__ inline float tmax16(const float4v* s) {
    float a = max3f(s[0][0], s[0][1], s[0][2]);
    float b = max3f(s[0][3], s[1][0], s[1][1]);
    float c = max3f(s[1][2], s[1][3], s[2][0]);
    float d = max3f(s[2][1], s[2][2], s[2][3]);
    float e = max3f(s[3][0], s[3][1], s[3][2]);
    float f = max3f(a, b, c);
    float g = max3f(d, e, s[3][3]);
    return fmaxf(f, g);
}

// ---------------------------------------------------------------------------
// prep kernel (verbatim round 6): merged convert_x + wpack.
// ---------------------------------------------------------------------------
__global__ __launch_bounds__(256) void prep_kernel(
    const float* __restrict__ xq, const float* __restrict__ xk,
    const float* __restrict__ xv,
    const float* __restrict__ wq, const float* __restrict__ wk,
    const float* __restrict__ wv, const float* __restrict__ wm,
    u16* __restrict__ xt_ws, u16* __restrict__ wbf)
{
    const int bid = blockIdx.x;
    const int tid = threadIdx.x;

    if (bid >= 1536) {                  // ---- wpack part
        const int id = bid - 1536;
        const int sr = id & 255, m = id >> 8;
        const float* W = (m == 0) ? wq : (m == 1) ? wk : (m == 2) ? wv : wm;
        float v;
        if (m < 3) {
            int og = (sr & ~15) | ((sr & 3) << 2) | ((sr >> 2) & 3);
            v = W[(size_t)og * DMODEL + tid];
        } else {
            int c = ((tid & 63) << 2) | (tid >> 6);
            v = W[(size_t)sr * DMODEL + c];
        }
        wbf[(size_t)m * 65536 + (size_t)sr * DMODEL + tid] = f2bf(v);
        return;
    }

    // ---- convert_x part
    const int nt = bid & 31;
    const int ct = (bid >> 5) & 3;
    const int z  = bid >> 7;            // 0..11
    const int b = z / 3, mode = z % 3;
    const float* X = ((mode == 0) ? xq : (mode == 1) ? xk : xv) + (size_t)b * DMODEL * NSEQ;
    u16* dst = xt_ws + (size_t)z * NSEQ * DMODEL;

    __shared__ u16 t[64][72];

    #pragma unroll
    for (int i = 0; i < 4; i++) {
        int e = tid + i * 256;
        int c = e >> 4;
        int n4 = (e & 15) * 4;
        float4v v = *(const float4v*)&X[(size_t)(ct * 64 + c) * NSEQ + nt * 64 + n4];
        #pragma unroll
        for (int j = 0; j < 4; j++) {
            int row = n4 + j;
            int fr = (row & 7) ^ ((row >> 3) & 7);
            t[row][(((c >> 3) ^ fr) << 3) + (c & 7)] = f2bf(v[j]);
        }
    }
    __syncthreads();
    #pragma unroll
    for (int i = 0; i < 4; i++) {
        int e = tid + i * 256;
        int n = e >> 4;
        int cb = (e & 15) * 4;
        int fr = (n & 7) ^ ((n >> 3) & 7);
        uint2v val = *(const uint2v*)&t[n][(((cb >> 3) ^ fr) << 3) + (cb & 7)];
        *(uint2v*)&dst[(size_t)(nt * 64 + n) * DMODEL + ct * 64 + cb] = val;
    }
}

// ---------------------------------------------------------------------------
// proj_qkv (verbatim round 6).
// ---------------------------------------------------------------------------
__global__ __launch_bounds__(256) void proj_qkv_kernel(
    const u16* __restrict__ xt_ws, const u16* __restrict__ wbf,
    const float* __restrict__ bqp, const float* __restrict__ bkp, const float* __restrict__ bvp,
    u16* __restrict__ q_ws, u16* __restrict__ k_ws, u16* __restrict__ vt_ws)
{
    const int nt0 = blockIdx.x, ot = blockIdx.y, bz = blockIdx.z;
    const int b = bz / 3, mode = bz % 3;
    const float* BI = (mode == 0) ? bqp : (mode == 1) ? bkp : bvp;

    const int tid = threadIdx.x;
    const int wave = tid >> 6, lane = tid & 63;
    const int g = lane >> 4, ql = lane & 15;
    const int srow8 = lane >> 3, su = lane & 7;
    const int u_l = su ^ srow8;
    const int obase = ot * 64, nbase = nt0 * 64;

    const u16* Asrc = wbf + (size_t)mode * 65536;
    const u16* Bsrc = xt_ws + (size_t)bz * (NSEQ * DMODEL);

    __shared__ u16 at[2][64][64];
    __shared__ u16 bt[2][64][64];

    float4v acc[4];
    #pragma unroll
    for (int i = 0; i < 4; i++) acc[i] = (float4v){0.f, 0.f, 0.f, 0.f};

    #define PSTAGE(bufi_, c0_)                                                         \
        { _Pragma("unroll")                                                            \
          for (int p_ = 0; p_ < 2; p_++) {                                             \
            int rb_ = wave * 8 + p_ * 32;                                              \
            int row_ = rb_ + srow8;                                                    \
            __builtin_amdgcn_global_load_lds(                                          \
                (const AS1 unsigned int*)(Asrc + (size_t)(obase + row_) * DMODEL + (c0_) + u_l * 8), \
                (AS3 unsigned int*)&at[bufi_][rb_][0], 16, 0, 0);                      \
            __builtin_amdgcn_global_load_lds(                                          \
                (const AS1 unsigned int*)(Bsrc + (size_t)(nbase + row_) * DMODEL + (c0_) + u_l * 8), \
                (AS3 unsigned int*)&bt[bufi_][rb_][0], 16, 0, 0);                      \
          } }

    PSTAGE(0, 0)
    __syncthreads();
    int buf = 0;
    const int sw = ql & 7;
    #pragma unroll
    for (int t = 0; t < 4; t++) {
        if (t < 3) PSTAGE(buf ^ 1, (t + 1) * 64)
        #pragma unroll
        for (int kc = 0; kc < 2; kc++) {
            short8 afrag = *(const short8*)&at[buf][wave * 16 + ql][(((kc * 4 + g) ^ sw)) * 8];
            #pragma unroll
            for (int nt = 0; nt < 4; nt++) {
                short8 bfrag = *(const short8*)&bt[buf][nt * 16 + ql][(((kc * 4 + g) ^ sw)) * 8];
                acc[nt] = __builtin_amdgcn_mfma_f32_16x16x32_bf16(afrag, bfrag, acc[nt], 0, 0, 0);
            }
        }
        __syncthreads();
        buf ^= 1;
    }
    #undef PSTAGE

    const int h = g;
    const int d0 = (obase + wave * 16) >> 2;
    float bias[4];
    #pragma unroll
    for (int r = 0; r < 4; r++) bias[r] = BI[obase + wave * 16 + 4 * r + g];

    #pragma unroll
    for (int nt = 0; nt < 4; nt++) {
        int n = nbase + nt * 16 + ql;
        float v[4];
        #pragma unroll
        for (int r = 0; r < 4; r++) v[r] = acc[nt][r] + bias[r];
        if (mode == 0) {
            #pragma unroll
            for (int r = 0; r < 4; r++) v[r] *= 0.18033688011112042f;  // 0.125*log2(e)
            uint2v pk = {pack2bf(v[0], v[1]), pack2bf(v[2], v[3])};
            *(uint2v*)&q_ws[((size_t)(b * NH + h) * NSEQ + n) * DHEAD + d0] = pk;
        } else if (mode == 1) {
            uint2v pk = {pack2bf(v[0], v[1]), pack2bf(v[2], v[3])};
            *(uint2v*)&k_ws[((size_t)(b * NH + h) * NSEQ + n) * DHEAD + d0] = pk;
        } else {
            #pragma unroll
            for (int r = 0; r < 4; r++)
                vt_ws[((size_t)(b * NH + h) * DHEAD + d0 + r) * NSEQ + n] = f2bf(v[r]);
        }
    }
}

// ---------------------------------------------------------------------------
// Flash attention v6: K-SPLIT. 512 blocks (2/CU, 4 waves/SIMD), 8 waves x
// 16 q; each block processes HALF the keys (1024). Writes unnormalized fp32
// partial O (float4) + per-row (m,l); merge happens in proj_out staging.
// ---------------------------------------------------------------------------
__global__ __launch_bounds__(512) void attn_kernel(
    const u16* __restrict__ q_ws, const u16* __restrict__ k_ws,
    const u16* __restrict__ vt_ws, float* __restrict__ part_ws,
    float* __restrict__ ml_ws)
{
    const int bid = blockIdx.x;
    const int orig = (bid & 7) * 64 + (bid >> 3);   // bijective XCD swizzle
    const int bh = orig >> 5;                        // 0..15 (2 bh per XCD)
    const int qt128 = (orig >> 1) & 15;              // 0..15
    const int half = orig & 1;                       // key half
    const int tid = threadIdx.x;
    const int wave = tid >> 6, lane = tid & 63;
    const int g = lane >> 4, ql = lane & 15;
    const int qbase = qt128 * 128 + wave * 16;

    const u16* qp = q_ws + ((size_t)bh * NSEQ + qbase) * DHEAD;
    const u16* kp = k_ws + (size_t)bh * NSEQ * DHEAD + (size_t)half * 1024 * DHEAD;
    const u16* vp = vt_ws + (size_t)bh * DHEAD * NSEQ;
    const int voff = half * 1024;

    __shared__ u16 kt[2][64][64];
    __shared__ u16 vt[2][64][64];
    __shared__ u16 p_lds[8][16][72];

    const int srow = lane >> 3;          // 0..7
    const int su_l = lane & 7;
    const int u_l  = su_l ^ srow;
    const int swz  = ql & 7;

    short8 qf[2];
    #pragma unroll
    for (int kc = 0; kc < 2; kc++)
        qf[kc] = *(const short8*)(qp + (size_t)ql * DHEAD + kc * 32 + g * 8);

    float4v acc[4];
    #pragma unroll
    for (int t = 0; t < 4; t++) acc[t] = (float4v){0.f, 0.f, 0.f, 0.f};
    float mrun = -INFINITY, lrun = 0.f;

    #define STAGE(mb_, bufi_)                                                          \
        {                                                                              \
            int row_ = wave * 8 + srow;                                                \
            __builtin_amdgcn_global_load_lds(                                          \
                (const AS1 unsigned int*)(kp + (size_t)((mb_) + row_) * DHEAD + u_l * 8), \
                (AS3 unsigned int*)&kt[bufi_][wave * 8][0], 16, 0, 0);                 \
            __builtin_amdgcn_global_load_lds(                                          \
                (const AS1 unsigned int*)(vp + (size_t)row_ * NSEQ + voff + (mb_) + u_l * 8), \
                (AS3 unsigned int*)&vt[bufi_][wave * 8][0], 16, 0, 0);                 \
        }

    STAGE(0, 0);
    __syncthreads();

    int buf = 0;
    for (int t = 0; t < 16; t++) {
        const int mb = t * 64;
        if (t < 15) STAGE(mb + 64, buf ^ 1);

        // ---- S^T = K.Q^T from LDS
        float4v st[4];
        #pragma unroll
        for (int mt = 0; mt < 4; mt++) st[mt] = (float4v){0.f, 0.f, 0.f, 0.f};
        #pragma unroll
        for (int mt = 0; mt < 4; mt++) {
            #pragma unroll
            for (int kc = 0; kc < 2; kc++) {
                short8 kf = *(const short8*)&kt[buf][mt * 16 + ql][((kc * 4 + g) ^ swz) * 8];
                st[mt] = __builtin_amdgcn_mfma_f32_16x16x32_bf16(kf, qf[kc], st[mt], 0, 0, 0);
            }
        }

        // ---- tile max + cross-lane
        float tmax = tmax16(&st[0]);
        tmax = fmaxf(tmax, __shfl_xor(tmax, 16, 64));
        tmax = fmaxf(tmax, __shfl_xor(tmax, 32, 64));

        // ---- defer-max rescale (2^8 headroom, scores in log2 units)
        if (__any(tmax > mrun + 8.f)) {
            float mnew = fmaxf(mrun, tmax);
            float a = __builtin_amdgcn_exp2f(mrun - mnew);
            #pragma unroll
            for (int tt = 0; tt < 4; tt++)
                #pragma unroll
                for (int r = 0; r < 4; r++) acc[tt][r] *= a;
            lrun *= a;
            mrun = mnew;
        }

        // ---- P = exp2(S - m), row sums, P -> wave-private LDS (bf16)
        float psum = 0.f;
        #pragma unroll
        for (int mt = 0; mt < 4; mt++) {
            float p0 = __builtin_amdgcn_exp2f(st[mt][0] - mrun);
            float p1 = __builtin_amdgcn_exp2f(st[mt][1] - mrun);
            float p2 = __builtin_amdgcn_exp2f(st[mt][2] - mrun);
            float p3 = __builtin_amdgcn_exp2f(st[mt][3] - mrun);
            psum += (p0 + p1) + (p2 + p3);
            *(uint2v*)&p_lds[wave][ql][mt * 16 + g * 4] = (uint2v){pack2bf(p0, p1), pack2bf(p2, p3)};
        }
        psum += __shfl_xor(psum, 16, 64);
        psum += __shfl_xor(psum, 32, 64);
        lrun += psum;

        // ---- PV: x^T[d][q] += V^T[d][m] * P^T[m][q]
        #pragma unroll
        for (int kc = 0; kc < 2; kc++) {
            short8 pf = *(const short8*)&p_lds[wave][ql][kc * 32 + g * 8];
            #pragma unroll
            for (int tt = 0; tt < 4; tt++) {
                short8 vf = *(const short8*)&vt[buf][tt * 16 + ql][((kc * 4 + g) ^ swz) * 8];
                acc[tt] = __builtin_amdgcn_mfma_f32_16x16x32_bf16(vf, pf, acc[tt], 0, 0, 0);
            }
        }
        __syncthreads();
        buf ^= 1;
    }
    #undef STAGE

    // ---- epilogue: unnormalized fp32 partial O + (m,l)
    float* prow = part_ws + ((size_t)(half * 16 + bh) * NSEQ + qbase + ql) * 64;
    #pragma unroll
    for (int t = 0; t < 4; t++)
        *(float4v*)&prow[t * 16 + g * 4] = acc[t];
    if (g == 0) {
        *(float2v*)&ml_ws[((size_t)(half * 16 + bh) * NSEQ + qbase + ql) * 2] =
            (float2v){mrun, lrun};
    }
}

// ---------------------------------------------------------------------------
// proj_out v2: out = Wm_re @ merge(part0, part1) + bm.
// B-staging does the K-split LSE merge inline: x[h][n][d] =
//   (p0*2^(m0-m*) + p1*2^(m1-m*)) / (l0*2^(m0-m*) + l1*2^(m1-m*)).
// A via global_load_lds; single-buffered, 2 barriers per K-iter (4 iters).
// ---------------------------------------------------------------------------
__global__ __launch_bounds__(256) void proj_out_kernel(
    const float* __restrict__ part_ws, const float* __restrict__ ml_ws,
    const u16* __restrict__ wbf, const float* __restrict__ bm,
    float* __restrict__ out)
{
    const int nt0 = blockIdx.x, ot = blockIdx.y, b = blockIdx.z;

    const int tid = threadIdx.x;
    const int wave = tid >> 6, lane = tid & 63;
    const int g = lane >> 4, ql = lane & 15;
    const int srow8 = lane >> 3, su = lane & 7;
    const int u_l = su ^ srow8;
    const int obase = ot * 64, nbase = nt0 * 64;

    const u16* Asrc = wbf + (size_t)3 * 65536;

    __shared__ u16 at[64][64];
    __shared__ u16 bt[64][64];

    float4v acc[4];
    #pragma unroll
    for (int i = 0; i < 4; i++) acc[i] = (float4v){0.f, 0.f, 0.f, 0.f};

    const int rrow = tid >> 2;           // 0..63 (B-merge row)
    const int qcol = tid & 3;            // 16-float chunk within row
    const int sw = ql & 7;

    #pragma unroll
    for (int t = 0; t < 4; t++) {
        const int c0 = t * 64;
        __syncthreads();                 // previous iter's reads done
        // ---- A stage (gload_lds, swizzled-source)
        #pragma unroll
        for (int p_ = 0; p_ < 2; p_++) {
            int rb_ = wave * 8 + p_ * 32;
            int row_ = rb_ + srow8;
            __builtin_amdgcn_global_load_lds(
                (const AS1 unsigned int*)(Asrc + (size_t)(obase + row_) * DMODEL + c0 + u_l * 8),
                (AS3 unsigned int*)&at[rb_][0], 16, 0, 0);
        }
        // ---- B stage: merge K-split partials -> bf16 -> swizzled LDS
        {
            const int bh = b * NH + t;   // head = c0>>6
            const int n = nbase + rrow;
            const float* p0 = part_ws + ((size_t)bh * NSEQ + n) * 64;
            const float* p1 = part_ws + ((size_t)(16 + bh) * NSEQ + n) * 64;
            float2v ml0 = *(const float2v*)&ml_ws[((size_t)bh * NSEQ + n) * 2];
            float2v ml1 = *(const float2v*)&ml_ws[((size_t)(16 + bh) * NSEQ + n) * 2];
            float mM = fmaxf(ml0[0], ml1[0]);
            float e0 = __builtin_amdgcn_exp2f(ml0[0] - mM);
            float e1 = __builtin_amdgcn_exp2f(ml1[0] - mM);
            float inv = 1.f / (ml0[1] * e0 + ml1[1] * e1);
            float s0 = e0 * inv, s1 = e1 * inv;
            #pragma unroll
            for (int j = 0; j < 4; j++) {
                int cb = qcol * 16 + j * 4;
                float4v f0 = *(const float4v*)&p0[cb];
                float4v f1 = *(const float4v*)&p1[cb];
                float x0 = f0[0] * s0 + f1[0] * s1;
                float x1 = f0[1] * s0 + f1[1] * s1;
                float x2 = f0[2] * s0 + f1[2] * s1;
                float x3 = f0[3] * s0 + f1[3] * s1;
                *(uint2v*)&bt[rrow][(((cb >> 3) ^ (rrow & 7)) << 3) + (cb & 7)] =
                    (uint2v){pack2bf(x0, x1), pack2bf(x2, x3)};
            }
        }
        __syncthreads();                 // staging (vmcnt+lgkm drained) done
        // ---- MFMA
        #pragma unroll
        for (int kc = 0; kc < 2; kc++) {
            short8 afrag = *(const short8*)&at[wave * 16 + ql][(((kc * 4 + g) ^ sw)) * 8];
            #pragma unroll
            for (int nt = 0; nt < 4; nt++) {
                short8 bfrag = *(const short8*)&bt[nt * 16 + ql][(((kc * 4 + g) ^ sw)) * 8];
                acc[nt] = __builtin_amdgcn_mfma_f32_16x16x32_bf16(afrag, bfrag, acc[nt], 0, 0, 0);
            }
        }
    }

    const int o0 = obase + wave * 16 + g * 4;
    #pragma unroll
    for (int nt = 0; nt < 4; nt++) {
        int n = nbase + nt * 16 + ql;
        #pragma unroll
        for (int r = 0; r < 4; r++) {
            int o = o0 + r;
            out[((size_t)b * DMODEL + o) * NSEQ + n] = acc[nt][r] + bm[o];
        }
    }
}

// ---------------------------------------------------------------------------
extern "C" void kernel_launch(void* const* d_in, const int* in_sizes, int n_in,
                              void* d_out, int out_size, void* d_ws, size_t ws_size,
                              hipStream_t stream)
{
    const float* query = (const float*)d_in[0];
    const float* key   = (const float*)d_in[1];
    const float* value = (const float*)d_in[2];
    const float* wq = (const float*)d_in[3];
    const float* bq = (const float*)d_in[4];
    const float* wk = (const float*)d_in[5];
    const float* bk = (const float*)d_in[6];
    const float* wv = (const float*)d_in[7];
    const float* bv = (const float*)d_in[8];
    const float* wm = (const float*)d_in[9];
    const float* bm = (const float*)d_in[10];
    float* out = (float*)d_out;

    char* ws = (char*)d_ws;
    const size_t SEG = (size_t)NB * NH * NSEQ * DHEAD * sizeof(u16);      // 4 MiB
    u16*   q_ws    = (u16*)(ws);
    u16*   k_ws    = (u16*)(ws + SEG);
    u16*   vt_ws   = (u16*)(ws + 2 * SEG);
    float* part_ws = (float*)(ws + 3 * SEG);                              // 16 MiB
    float* ml_ws   = (float*)(ws + 3 * SEG + (size_t)2 * 16 * NSEQ * 64 * sizeof(float));
    char*  after_ml = ws + 3 * SEG + (size_t)2 * 16 * NSEQ * 64 * sizeof(float)
                         + (size_t)2 * 16 * NSEQ * 2 * sizeof(float);
    u16*   xt_ws   = (u16*)(after_ml);                                    // 12 MiB
    u16*   wbf     = (u16*)(after_ml + (size_t)12 * NSEQ * DMODEL * sizeof(u16));

    prep_kernel<<<dim3(2560), 256, 0, stream>>>(
        query, key, value, wq, wk, wv, wm, xt_ws, wbf);
    proj_qkv_kernel<<<dim3(32, 4, 12), 256, 0, stream>>>(
        xt_ws, wbf, bq, bk, bv, q_ws, k_ws, vt_ws);
    attn_kernel<<<dim3(512), 512, 0, stream>>>(q_ws, k_ws, vt_ws, part_ws, ml_ws);
    proj_out_kernel<<<dim3(32, 4, NB), 256, 0, stream>>>(part_ws, ml_ws, wbf, bm, out);
}